// Round 2
// baseline (8375.256 us; speedup 1.0000x reference)
//
#include <hip/hip_runtime.h>

// VQ-VAE vector quantizer, MI355X.
// N=16384 tokens, D=512, K=8192 codes, all f32.
// out0: quantized_st [N*D], out1: vq_loss [N], out2: encoding_inds [N] (as float)
//
// The reference argmin is over an f32 computation: dist = fl(fl(sumx2 + sume2) - fl(2*M)),
// with dist ~ 512 quantized to ulp(512)=6.1e-5 while top-2 gaps avg 7.6e-4 -> ties are
// common and np.argmin picks the LOWEST index. We therefore: (1) rank by f32 dot (GEMM),
// (2) for all candidates within 1e-4 of the max dot, reconstruct the reference's f32
// grid value exactly (numpy-pairwise sums, f64->f32 rounded matmul) and pick
// (min value, min index).

#define D_DIM   512
#define K_CODES 8192
#define N_TOK   16384
#define BM      64
#define BK      128
#define DC      64

// numpy pairwise sum of a[i]^2 over 512 contiguous f32, exact semantics:
// four 128-blocks (8 accumulators, step 8, ((r0+r1)+(r2+r3))+((r4+r5)+(r6+r7))),
// combined as (B0+B1)+(B2+B3). Squares via f64 mul + cvt = exactly fl32(a*a),
// and the cvt blocks FMA contraction of the accumulate.
__device__ __forceinline__ float np_pairwise_sq(const float* __restrict__ a) {
    float blk[4];
#pragma unroll
    for (int b = 0; b < 4; ++b) {
        const float* p = a + b * 128;
        float r[8];
#pragma unroll
        for (int j = 0; j < 8; ++j) { double d = (double)p[j]; r[j] = (float)(d * d); }
        for (int i = 8; i < 128; i += 8) {
#pragma unroll
            for (int j = 0; j < 8; ++j) { double d = (double)p[i + j]; r[j] = r[j] + (float)(d * d); }
        }
        blk[b] = ((r[0] + r[1]) + (r[2] + r[3])) + ((r[4] + r[5]) + (r[6] + r[7]));
    }
    return (blk[0] + blk[1]) + (blk[2] + blk[3]);
}

__global__ __launch_bounds__(512) void vq_argmin_kernel(
    const float* __restrict__ X,   // [N_TOK, D]
    const float* __restrict__ E,   // [K_CODES, D]
    float* __restrict__ out_idx)   // [N_TOK] float-encoded ints
{
    __shared__ __align__(16) unsigned char smem[48 * 1024];
    float4* Xs = (float4*)smem;                 // [64][16 f4] swizzled
    float4* Es = (float4*)(smem + 16 * 1024);   // [128][16 f4] swizzled
    float*  cv = (float*)smem;                  // [64][64] candidate dots (epilogue)
    int*    ci = (int*)(smem + 16 * 1024);      // [64][64] candidate indices

    const int t    = threadIdx.x;
    const int tc   = t & 31;
    const int tr   = t >> 5;
    const int tok0 = blockIdx.x * BM;

    const float4* Xg = (const float4*)X;  // row stride 128 f4
    const float4* Eg = (const float4*)E;

    float v0[4], v1[4];
    int   i0[4], i1[4];
#pragma unroll
    for (int i = 0; i < 4; ++i) { v0[i] = -1e30f; v1[i] = -1e30f; i0[i] = 0; i1[i] = 1; }

    for (int kt = 0; kt < K_CODES / BK; ++kt) {
        float acc[4][4];
#pragma unroll
        for (int i = 0; i < 4; ++i)
#pragma unroll
            for (int j = 0; j < 4; ++j) acc[i][j] = 0.f;

        for (int dc = 0; dc < D_DIM / DC; ++dc) {
            __syncthreads();
#pragma unroll
            for (int s = 0; s < 2; ++s) {
                int id = t + s * 512;
                int r = id >> 4, m = id & 15;
                float4 val = Xg[(size_t)(tok0 + r) * 128 + dc * 16 + m];
                Xs[r * 16 + ((m + (r >> 2)) & 15)] = val;
            }
#pragma unroll
            for (int s = 0; s < 4; ++s) {
                int id = t + s * 512;
                int r = id >> 4, m = id & 15;
                float4 val = Eg[(size_t)(kt * BK + r) * 128 + dc * 16 + m];
                Es[r * 16 + ((m + (r >> 2)) & 15)] = val;
            }
            __syncthreads();

#pragma unroll
            for (int dd4 = 0; dd4 < 16; ++dd4) {
                float4 xv[4], ev[4];
#pragma unroll
                for (int i = 0; i < 4; ++i)
                    xv[i] = Xs[(4 * tr + i) * 16 + ((dd4 + tr) & 15)];
#pragma unroll
                for (int j = 0; j < 4; ++j)
                    ev[j] = Es[(4 * tc + j) * 16 + ((dd4 + tc) & 15)];
#pragma unroll
                for (int i = 0; i < 4; ++i)
#pragma unroll
                    for (int j = 0; j < 4; ++j) {
                        acc[i][j] += xv[i].x * ev[j].x + xv[i].y * ev[j].y
                                   + xv[i].z * ev[j].z + xv[i].w * ev[j].w;
                    }
            }
        }
#pragma unroll
        for (int i = 0; i < 4; ++i) {
#pragma unroll
            for (int j = 0; j < 4; ++j) {
                float v  = acc[i][j];
                int  idx = kt * BK + 4 * tc + j;
                if (v > v0[i])      { v1[i] = v0[i]; i1[i] = i0[i]; v0[i] = v; i0[i] = idx; }
                else if (v > v1[i]) { v1[i] = v; i1[i] = idx; }
            }
        }
    }

    __syncthreads();
#pragma unroll
    for (int i = 0; i < 4; ++i) {
        int row = 4 * tr + i;
        cv[row * 64 + 2 * tc]     = v0[i]; ci[row * 64 + 2 * tc]     = i0[i];
        cv[row * 64 + 2 * tc + 1] = v1[i]; ci[row * 64 + 2 * tc + 1] = i1[i];
    }
    __syncthreads();

    if (t < BM) {
        const int row = t;
        // max f32 dot among the 64 candidates
        float b0 = -1e30f;
        for (int s = 0; s < 64; ++s) b0 = fmaxf(b0, cv[row * 64 + s]);

        const float* xr = X + (size_t)(tok0 + row) * D_DIM;
        const float sumx2 = np_pairwise_sq(xr);   // numpy-exact fl32 sum of x^2

        // refine every candidate within the tie window (needs ~3.1e-5; use 1e-4)
        float bd = 1e30f;
        int   bi = 0x7fffffff;
        for (int s = 0; s < 64; ++s) {
            float v = cv[row * 64 + s];
            if (v < b0 - 1.0e-4f) continue;
            int idx = ci[row * 64 + s];
            const float* er = E + (size_t)idx * D_DIM;
            // matmul entry: exact f64 dot rounded once to f32 (~sgemm within ~2e-10)
            double acc = 0.0;
            for (int d0 = 0; d0 < D_DIM; ++d0)
                acc += (double)xr[d0] * (double)er[d0];
            float M  = (float)acc;
            float se = np_pairwise_sq(er);        // numpy-exact fl32 sum of e^2
            float S  = sumx2 + se;                // f32 broadcast add, as in reference
            float d  = S - 2.0f * M;              // f32 subtract -> the quantized grid value
            if (d < bd || (d == bd && idx < bi)) { bd = d; bi = idx; }
        }
        out_idx[tok0 + row] = (float)bi;
    }
}

__global__ __launch_bounds__(128) void vq_gather_kernel(
    const float* __restrict__ X,
    const float* __restrict__ E,
    const float* __restrict__ idxf,
    float* __restrict__ outq,
    float* __restrict__ outl)
{
    const int n = blockIdx.x;
    const int t = threadIdx.x;
    const int idx = (int)idxf[n];

    const float4* xr = (const float4*)(X + (size_t)n * D_DIM);
    const float4* er = (const float4*)(E + (size_t)idx * D_DIM);
    float4*       qr = (float4*)(outq + (size_t)n * D_DIM);

    float4 x = xr[t], e = er[t];
    float4 dl; dl.x = e.x - x.x; dl.y = e.y - x.y; dl.z = e.z - x.z; dl.w = e.w - x.w;
    float4 q;  q.x = x.x + dl.x; q.y = x.y + dl.y; q.z = x.z + dl.z; q.w = x.w + dl.w;
    qr[t] = q;

    float s = dl.x * dl.x + dl.y * dl.y + dl.z * dl.z + dl.w * dl.w;
#pragma unroll
    for (int off = 32; off > 0; off >>= 1) s += __shfl_down(s, off, 64);

    __shared__ float red[2];
    if ((t & 63) == 0) red[t >> 6] = s;
    __syncthreads();
    if (t == 0) {
        float m = (red[0] + red[1]) * (1.0f / (float)D_DIM);
        outl[n] = m + 0.25f * m;
    }
}

extern "C" void kernel_launch(void* const* d_in, const int* in_sizes, int n_in,
                              void* d_out, int out_size, void* d_ws, size_t ws_size,
                              hipStream_t stream) {
    const float* X = (const float*)d_in[0];
    const float* E = (const float*)d_in[1];
    float* out  = (float*)d_out;
    float* outq = out;
    float* outl = out + (size_t)N_TOK * D_DIM;
    float* outi = outl + N_TOK;

    vq_argmin_kernel<<<N_TOK / BM, 512, 0, stream>>>(X, E, outi);
    vq_gather_kernel<<<N_TOK, 128, 0, stream>>>(X, E, outi, outq, outl);
}

// Round 3
// 827.185 us; speedup vs baseline: 10.1250x; 10.1250x over previous
//
#include <hip/hip_runtime.h>

// VQ-VAE vector quantizer, MI355X. N=16384 tokens, D=512, K=8192 codes, f32.
// out0: quantized_st [N*D], out1: vq_loss [N], out2: encoding_inds [N] (as float)
//
// Pass-1 ranks codes by dot(x,e) via bf16 hi/lo split MFMA (err ~1e-8 << 3.05e-5 tie
// window); candidates within 1e-4 of max dot are exact-refined on the reference's
// f32 grid (numpy-pairwise sums, f64->f32 rounded matmul), lowest-index tie-break.

#define D_DIM   512
#define K_CODES 8192
#define N_TOK   16384

typedef short bf16x8 __attribute__((ext_vector_type(8)));
typedef float f32x16 __attribute__((ext_vector_type(16)));

// numpy pairwise sum of a[i]^2 over 512 f32 (exact reference semantics).
__device__ __forceinline__ float np_pairwise_sq(const float* __restrict__ a) {
    float blk[4];
#pragma unroll
    for (int b = 0; b < 4; ++b) {
        const float* p = a + b * 128;
        float r[8];
#pragma unroll
        for (int j = 0; j < 8; ++j) { double d = (double)p[j]; r[j] = (float)(d * d); }
        for (int i = 8; i < 128; i += 8) {
#pragma unroll
            for (int j = 0; j < 8; ++j) { double d = (double)p[i + j]; r[j] = r[j] + (float)(d * d); }
        }
        blk[b] = ((r[0] + r[1]) + (r[2] + r[3])) + ((r[4] + r[5]) + (r[6] + r[7]));
    }
    return (blk[0] + blk[1]) + (blk[2] + blk[3]);
}

__device__ __forceinline__ unsigned short f2bf(float x) {
    unsigned u = __float_as_uint(x);
    return (unsigned short)((u + 0x7fffu + ((u >> 16) & 1u)) >> 16);
}

// ---------- pre-pass: X,E -> pre-swizzled bf16 hi/lo tile images ----------
// Layout: [blk256][dc 0..7][fmt hi/lo][row 256][slot 8][16B], slot = (k>>3) ^ (row&7).
__global__ __launch_bounds__(256) void vq_convert(
    const float* __restrict__ X, const float* __restrict__ E,
    unsigned char* __restrict__ Xt, unsigned char* __restrict__ Et)
{
    int tid = blockIdx.x * 256 + threadIdx.x;
    const float* src; unsigned char* dst; int n, sg;
    if (tid < N_TOK * 64) { n = tid >> 6; sg = tid & 63; src = X; dst = Xt; }
    else { int m = tid - N_TOK * 64; n = m >> 6; sg = m & 63; src = E; dst = Et; }
    int blk = n >> 8, r = n & 255, dc = sg >> 3, sl = sg & 7;
    const float* p = src + (size_t)n * D_DIM + sg * 8;
    float4 a = *(const float4*)(p);
    float4 b = *(const float4*)(p + 4);
    float xs[8] = { a.x, a.y, a.z, a.w, b.x, b.y, b.z, b.w };
    unsigned h[8], l[8];
#pragma unroll
    for (int j = 0; j < 8; ++j) {
        unsigned short hh = f2bf(xs[j]);
        float hf = __uint_as_float((unsigned)hh << 16);
        unsigned short ll = f2bf(xs[j] - hf);
        h[j] = hh; l[j] = ll;
    }
    uint4 hv = make_uint4(h[0] | (h[1] << 16), h[2] | (h[3] << 16), h[4] | (h[5] << 16), h[6] | (h[7] << 16));
    uint4 lv = make_uint4(l[0] | (l[1] << 16), l[2] | (l[3] << 16), l[4] | (l[5] << 16), l[6] | (l[7] << 16));
    size_t base = (size_t)(blk * 8 + dc) * 65536 + (size_t)r * 128 + (size_t)((sl ^ (r & 7)) * 16);
    *(uint4*)(dst + base) = hv;
    *(uint4*)(dst + base + 32768) = lv;
}

// ---------- pass-1 GEMM: block = 256 tokens x 2048 codes, BK=64, 8 waves ----------
__global__ __launch_bounds__(512, 2) void vq_gemm(
    const unsigned char* __restrict__ Xt, const unsigned char* __restrict__ Et,
    float* __restrict__ vbuf, int* __restrict__ ibuf)
{
    __shared__ unsigned int smemU[32768];  // 128 KiB: Ea(codes) 64K @0, Xb(tokens) 64K @65536
    const int tid  = threadIdx.x;
    const int lane = tid & 63, w = tid >> 6;
    const int tg = w >> 1, cg = w & 1;           // wave grid: 4 token-groups x 2 code-groups
    const int hi5 = lane >> 5, l31 = lane & 31;
    const int r7 = l31 & 7;
    const int tb = blockIdx.x >> 2, q = blockIdx.x & 3;

    float v0[2], v1[2]; int i0[2], i1[2];
#pragma unroll
    for (int tf = 0; tf < 2; ++tf) { v0[tf] = -1e30f; v1[tf] = -1e30f; i0[tf] = 0; i1[tf] = 1; }

    for (int ck = 0; ck < 8; ++ck) {
        const int cb = q * 8 + ck;
        f32x16 acc[4][2] = {};
        for (int dc = 0; dc < 8; ++dc) {
            __syncthreads();
            const unsigned char* srcE = Et + (size_t)(cb * 8 + dc) * 65536;
            const unsigned char* srcX = Xt + (size_t)(tb * 8 + dc) * 65536;
#pragma unroll
            for (int p = 0; p < 8; ++p) {
                int off = (p * 8 + w) * 1024;
                __builtin_amdgcn_global_load_lds((const unsigned int*)(srcE + off + lane * 16),
                                                 smemU + (off >> 2), 16, 0, 0);
            }
#pragma unroll
            for (int p = 0; p < 8; ++p) {
                int off = (p * 8 + w) * 1024;
                __builtin_amdgcn_global_load_lds((const unsigned int*)(srcX + off + lane * 16),
                                                 smemU + ((65536 + off) >> 2), 16, 0, 0);
            }
            __syncthreads();

            // B-operand (tokens) fragments, resident: [fmt][tf][s]
            bf16x8 Bf[2][2][4];
#pragma unroll
            for (int tf = 0; tf < 2; ++tf) {
                int row = tg * 64 + tf * 32 + l31;
#pragma unroll
                for (int s = 0; s < 4; ++s) {
                    int slot = (((s * 2 + hi5) ^ r7) * 16);
#pragma unroll
                    for (int f = 0; f < 2; ++f)
                        Bf[f][tf][s] = *(const bf16x8*)((const unsigned char*)smemU + 65536 + f * 32768 + row * 128 + slot);
                }
            }
#pragma unroll
            for (int cf = 0; cf < 4; ++cf) {
                int rowA = cg * 128 + cf * 32 + l31;
                bf16x8 Af[2][4];
#pragma unroll
                for (int s = 0; s < 4; ++s) {
                    int slot = (((s * 2 + hi5) ^ r7) * 16);
#pragma unroll
                    for (int f = 0; f < 2; ++f)
                        Af[f][s] = *(const bf16x8*)((const unsigned char*)smemU + f * 32768 + rowA * 128 + slot);
                }
#pragma unroll
                for (int tf = 0; tf < 2; ++tf) {
#pragma unroll
                    for (int s = 0; s < 4; ++s) {
                        acc[cf][tf] = __builtin_amdgcn_mfma_f32_32x32x16_bf16(Af[0][s], Bf[0][tf][s], acc[cf][tf], 0, 0, 0);
                        acc[cf][tf] = __builtin_amdgcn_mfma_f32_32x32x16_bf16(Af[0][s], Bf[1][tf][s], acc[cf][tf], 0, 0, 0);
                        acc[cf][tf] = __builtin_amdgcn_mfma_f32_32x32x16_bf16(Af[1][s], Bf[0][tf][s], acc[cf][tf], 0, 0, 0);
                    }
                }
            }
        }
        // top-2 insert per (lane, token-frag); ascending code order preserves low-index ties
#pragma unroll
        for (int tf = 0; tf < 2; ++tf) {
#pragma unroll
            for (int cf = 0; cf < 4; ++cf) {
#pragma unroll
                for (int g = 0; g < 16; ++g) {
                    float v = acc[cf][tf][g];
                    int code = cb * 256 + cg * 128 + cf * 32 + ((g & 3) + 8 * (g >> 2) + 4 * hi5);
                    if (v > v0[tf])      { v1[tf] = v0[tf]; i1[tf] = i0[tf]; v0[tf] = v; i0[tf] = code; }
                    else if (v > v1[tf]) { v1[tf] = v; i1[tf] = code; }
                }
            }
        }
    }
#pragma unroll
    for (int tf = 0; tf < 2; ++tf) {
        int tr = tg * 64 + tf * 32 + l31;
        size_t base = ((size_t)(blockIdx.x * 256 + tr)) * 8 + (size_t)((cg * 2 + hi5) * 2);
        vbuf[base] = v0[tf];     ibuf[base] = i0[tf];
        vbuf[base + 1] = v1[tf]; ibuf[base + 1] = i1[tf];
    }
}

// ---------- refine: merge 32 candidates/token, exact f32-grid reconstruction ----------
__global__ __launch_bounds__(256) void vq_refine(
    const float* __restrict__ X, const float* __restrict__ E,
    const float* __restrict__ vbuf, const int* __restrict__ ibuf,
    float* __restrict__ out_idx)
{
    int n = blockIdx.x * 256 + threadIdx.x;
    int tb = n >> 8, r = n & 255;
    float b0 = -1e30f;
    for (int qq = 0; qq < 4; ++qq)
#pragma unroll
        for (int s = 0; s < 8; ++s)
            b0 = fmaxf(b0, vbuf[((size_t)((tb * 4 + qq) * 256 + r)) * 8 + s]);

    const float* xr = X + (size_t)n * D_DIM;
    float sumx2 = np_pairwise_sq(xr);
    float bd = 1e30f; int bi = 2147483647;
    for (int qq = 0; qq < 4; ++qq) {
        for (int s = 0; s < 8; ++s) {
            size_t e0 = ((size_t)((tb * 4 + qq) * 256 + r)) * 8 + s;
            float v = vbuf[e0];
            if (v < b0 - 1.0e-4f) continue;
            int idx = ibuf[e0];
            const float* er = E + (size_t)idx * D_DIM;
            double acc = 0.0;
            for (int d0 = 0; d0 < D_DIM; ++d0)
                acc += (double)xr[d0] * (double)er[d0];
            float M  = (float)acc;
            float se = np_pairwise_sq(er);
            float S  = sumx2 + se;
            float d  = S - 2.0f * M;
            if (d < bd || (d == bd && idx < bi)) { bd = d; bi = idx; }
        }
    }
    out_idx[n] = (float)bi;
}

// ---------- fallback pass-1 (proven round-2 kernel, used only if ws too small) ----------
__global__ __launch_bounds__(512) void vq_argmin_kernel(
    const float* __restrict__ X, const float* __restrict__ E, float* __restrict__ out_idx)
{
    __shared__ __align__(16) unsigned char smem[48 * 1024];
    float4* Xs = (float4*)smem;
    float4* Es = (float4*)(smem + 16 * 1024);
    float*  cv = (float*)smem;
    int*    ci = (int*)(smem + 16 * 1024);
    const int t = threadIdx.x, tc = t & 31, tr = t >> 5;
    const int tok0 = blockIdx.x * 64;
    const float4* Xg = (const float4*)X;
    const float4* Eg = (const float4*)E;
    float v0[4], v1[4]; int i0[4], i1[4];
#pragma unroll
    for (int i = 0; i < 4; ++i) { v0[i] = -1e30f; v1[i] = -1e30f; i0[i] = 0; i1[i] = 1; }
    for (int kt = 0; kt < K_CODES / 128; ++kt) {
        float acc[4][4];
#pragma unroll
        for (int i = 0; i < 4; ++i)
#pragma unroll
            for (int j = 0; j < 4; ++j) acc[i][j] = 0.f;
        for (int dc = 0; dc < 8; ++dc) {
            __syncthreads();
#pragma unroll
            for (int s = 0; s < 2; ++s) {
                int id = t + s * 512; int rr = id >> 4, m = id & 15;
                Xs[rr * 16 + ((m + (rr >> 2)) & 15)] = Xg[(size_t)(tok0 + rr) * 128 + dc * 16 + m];
            }
#pragma unroll
            for (int s = 0; s < 4; ++s) {
                int id = t + s * 512; int rr = id >> 4, m = id & 15;
                Es[rr * 16 + ((m + (rr >> 2)) & 15)] = Eg[(size_t)(kt * 128 + rr) * 128 + dc * 16 + m];
            }
            __syncthreads();
#pragma unroll
            for (int dd4 = 0; dd4 < 16; ++dd4) {
                float4 xv[4], ev[4];
#pragma unroll
                for (int i = 0; i < 4; ++i) xv[i] = Xs[(4 * tr + i) * 16 + ((dd4 + tr) & 15)];
#pragma unroll
                for (int j = 0; j < 4; ++j) ev[j] = Es[(4 * tc + j) * 16 + ((dd4 + tc) & 15)];
#pragma unroll
                for (int i = 0; i < 4; ++i)
#pragma unroll
                    for (int j = 0; j < 4; ++j)
                        acc[i][j] += xv[i].x * ev[j].x + xv[i].y * ev[j].y + xv[i].z * ev[j].z + xv[i].w * ev[j].w;
            }
        }
#pragma unroll
        for (int i = 0; i < 4; ++i)
#pragma unroll
            for (int j = 0; j < 4; ++j) {
                float v = acc[i][j]; int idx = kt * 128 + 4 * tc + j;
                if (v > v0[i])      { v1[i] = v0[i]; i1[i] = i0[i]; v0[i] = v; i0[i] = idx; }
                else if (v > v1[i]) { v1[i] = v; i1[i] = idx; }
            }
    }
    __syncthreads();
#pragma unroll
    for (int i = 0; i < 4; ++i) {
        int row = 4 * tr + i;
        cv[row * 64 + 2 * tc] = v0[i];     ci[row * 64 + 2 * tc] = i0[i];
        cv[row * 64 + 2 * tc + 1] = v1[i]; ci[row * 64 + 2 * tc + 1] = i1[i];
    }
    __syncthreads();
    if (t < 64) {
        const int row = t;
        float b0 = -1e30f;
        for (int s = 0; s < 64; ++s) b0 = fmaxf(b0, cv[row * 64 + s]);
        const float* xr = X + (size_t)(tok0 + row) * D_DIM;
        const float sumx2 = np_pairwise_sq(xr);
        float bd = 1e30f; int bi = 0x7fffffff;
        for (int s = 0; s < 64; ++s) {
            float v = cv[row * 64 + s];
            if (v < b0 - 1.0e-4f) continue;
            int idx = ci[row * 64 + s];
            const float* er = E + (size_t)idx * D_DIM;
            double acc = 0.0;
            for (int d0 = 0; d0 < D_DIM; ++d0) acc += (double)xr[d0] * (double)er[d0];
            float M = (float)acc;
            float se = np_pairwise_sq(er);
            float S = sumx2 + se;
            float d = S - 2.0f * M;
            if (d < bd || (d == bd && idx < bi)) { bd = d; bi = idx; }
        }
        out_idx[tok0 + row] = (float)bi;
    }
}

__global__ __launch_bounds__(128) void vq_gather_kernel(
    const float* __restrict__ X, const float* __restrict__ E,
    const float* __restrict__ idxf, float* __restrict__ outq, float* __restrict__ outl)
{
    const int n = blockIdx.x, t = threadIdx.x;
    const int idx = (int)idxf[n];
    const float4* xr = (const float4*)(X + (size_t)n * D_DIM);
    const float4* er = (const float4*)(E + (size_t)idx * D_DIM);
    float4* qr = (float4*)(outq + (size_t)n * D_DIM);
    float4 x = xr[t], e = er[t];
    float4 dl; dl.x = e.x - x.x; dl.y = e.y - x.y; dl.z = e.z - x.z; dl.w = e.w - x.w;
    float4 qv; qv.x = x.x + dl.x; qv.y = x.y + dl.y; qv.z = x.z + dl.z; qv.w = x.w + dl.w;
    qr[t] = qv;
    float s = dl.x * dl.x + dl.y * dl.y + dl.z * dl.z + dl.w * dl.w;
#pragma unroll
    for (int off = 32; off > 0; off >>= 1) s += __shfl_down(s, off, 64);
    __shared__ float red[2];
    if ((t & 63) == 0) red[t >> 6] = s;
    __syncthreads();
    if (t == 0) {
        float m = (red[0] + red[1]) * (1.0f / (float)D_DIM);
        outl[n] = m + 0.25f * m;
    }
}

extern "C" void kernel_launch(void* const* d_in, const int* in_sizes, int n_in,
                              void* d_out, int out_size, void* d_ws, size_t ws_size,
                              hipStream_t stream) {
    const float* X = (const float*)d_in[0];
    const float* E = (const float*)d_in[1];
    float* out  = (float*)d_out;
    float* outq = out;
    float* outl = out + (size_t)N_TOK * D_DIM;
    float* outi = outl + N_TOK;

    const size_t WS_NEED = 54525952;  // Xt 32M + Et 16M + vbuf 2M + ibuf 2M
    if (ws_size >= WS_NEED) {
        unsigned char* ws = (unsigned char*)d_ws;
        unsigned char* Xt = ws;
        unsigned char* Et = ws + 33554432;
        float* vbuf = (float*)(ws + 50331648);
        int*   ibuf = (int*)(ws + 52428800);
        vq_convert<<<6144, 256, 0, stream>>>(X, E, Xt, Et);
        vq_gemm<<<256, 512, 0, stream>>>(Xt, Et, vbuf, ibuf);
        vq_refine<<<64, 256, 0, stream>>>(X, E, vbuf, ibuf, outi);
    } else {
        vq_argmin_kernel<<<N_TOK / 64, 512, 0, stream>>>(X, E, outi);
    }
    vq_gather_kernel<<<N_TOK, 128, 0, stream>>>(X, E, outi, outq, outl);
}

// Round 4
// 742.583 us; speedup vs baseline: 11.2785x; 1.1139x over previous
//
#include <hip/hip_runtime.h>

// VQ-VAE vector quantizer, MI355X. N=16384 tokens, D=512, K=8192 codes, f32.
// out0: quantized_st [N*D], out1: vq_loss [N], out2: encoding_inds [N] (as float)
//
// Pass-1: dot(x,e) ~ eh*(xh+xl) via MFMA (err ~2e-6 << tie window). E streamed
// global->reg as fragment lines (no LDS, no barriers); X resident in LDS full-D.
// Pass-2: exact f32-grid reconstruction (numpy-pairwise sums, f64->f32 dot),
// lowest-index tie-break. Window 1.2e-4 on approx dot.

#define D_DIM   512
#define K_CODES 8192
#define N_TOK   16384

typedef short bf16x8 __attribute__((ext_vector_type(8)));
typedef float f32x16 __attribute__((ext_vector_type(16)));

__device__ __forceinline__ unsigned short f2bf(float x) {
    unsigned u = __float_as_uint(x);
    return (unsigned short)((u + 0x7fffu + ((u >> 16) & 1u)) >> 16);
}

// exact numpy pairwise sum of squares over 512 f32 (serial-thread version, fallback path)
__device__ __forceinline__ float np_pairwise_sq(const float* __restrict__ a) {
    float blk[4];
#pragma unroll
    for (int b = 0; b < 4; ++b) {
        const float* p = a + b * 128;
        float r[8];
#pragma unroll
        for (int j = 0; j < 8; ++j) { double d = (double)p[j]; r[j] = (float)(d * d); }
        for (int i = 8; i < 128; i += 8) {
#pragma unroll
            for (int j = 0; j < 8; ++j) { double d = (double)p[i + j]; r[j] = r[j] + (float)(d * d); }
        }
        blk[b] = ((r[0] + r[1]) + (r[2] + r[3])) + ((r[4] + r[5]) + (r[6] + r[7]));
    }
    return (blk[0] + blk[1]) + (blk[2] + blk[3]);
}

// ---------- convert: build fragment-line images ----------
// Ximg: [tb 256][line2 64=(s*2+tf)][fmt 2][lane 64][16B]  (128KB per tb, 32MB)
// Eimg: [cb 256][s 32][lane 64][16B]                      (hi only, 8MB)
// lane = hi5*32 + (row&31); data = bf16x8 of row, d = s*16 + hi5*8 ..+7
__global__ __launch_bounds__(256) void vq_convert(
    const float* __restrict__ X, const float* __restrict__ E,
    unsigned char* __restrict__ Xim, unsigned char* __restrict__ Eim)
{
    int tid = blockIdx.x * 256 + threadIdx.x;
    if (tid < 1048576) {  // X path
        int tb = tid >> 12, rem = tid & 4095;
        int line2 = rem >> 6, lane = rem & 63;
        int s = line2 >> 1, tf = line2 & 1;
        int hi5 = lane >> 5, t31 = lane & 31;
        int token = tb * 64 + tf * 32 + t31;
        int d0 = s * 16 + hi5 * 8;
        const float* p = X + (size_t)token * D_DIM + d0;
        unsigned h[8], l[8];
#pragma unroll
        for (int j = 0; j < 8; ++j) {
            float x = p[j];
            unsigned short hh = f2bf(x);
            float hf = __uint_as_float((unsigned)hh << 16);
            unsigned short ll = f2bf(x - hf);
            h[j] = hh; l[j] = ll;
        }
        uint4 hv = make_uint4(h[0]|(h[1]<<16), h[2]|(h[3]<<16), h[4]|(h[5]<<16), h[6]|(h[7]<<16));
        uint4 lv = make_uint4(l[0]|(l[1]<<16), l[2]|(l[3]<<16), l[4]|(l[5]<<16), l[6]|(l[7]<<16));
        size_t base = (size_t)tb * 131072 + (size_t)(line2 * 2) * 1024 + (size_t)lane * 16;
        *(uint4*)(Xim + base) = hv;
        *(uint4*)(Xim + base + 1024) = lv;
    } else if (tid < 1572864) {  // E path (hi only)
        int id2 = tid - 1048576;
        int cb = id2 >> 11, rem = id2 & 2047;
        int s = rem >> 6, lane = rem & 63;
        int hi5 = lane >> 5, c31 = lane & 31;
        int code = cb * 32 + c31;
        int d0 = s * 16 + hi5 * 8;
        const float* p = E + (size_t)code * D_DIM + d0;
        unsigned h[8];
#pragma unroll
        for (int j = 0; j < 8; ++j) h[j] = f2bf(p[j]);
        uint4 hv = make_uint4(h[0]|(h[1]<<16), h[2]|(h[3]<<16), h[4]|(h[5]<<16), h[6]|(h[7]<<16));
        *(uint4*)(Eim + (size_t)cb * 32768 + (size_t)s * 1024 + (size_t)lane * 16) = hv;
    }
}

// ---------- rowsq: exact numpy-pairwise sum of squares, one 32-lane group per row ----------
__global__ __launch_bounds__(256) void vq_rowsq(
    const float* __restrict__ X, const float* __restrict__ E,
    float* __restrict__ sx, float* __restrict__ se)
{
    int t = threadIdx.x;
    int wv = blockIdx.x * 4 + (t >> 6);
    int sub = (t >> 5) & 1, l32 = t & 31;
    int row = wv * 2 + sub;
    const float* p;
    float* dst;
    if (row < N_TOK) { p = X + (size_t)row * D_DIM; dst = sx + row; }
    else if (row < N_TOK + K_CODES) { p = E + (size_t)(row - N_TOK) * D_DIM; dst = se + (row - N_TOK); }
    else return;
    int b = l32 >> 3, rr = l32 & 7;
    const float* q = p + b * 128 + rr;
    double d0 = (double)q[0];
    float r = (float)(d0 * d0);
#pragma unroll
    for (int i = 1; i < 16; ++i) { double d = (double)q[8 * i]; r = r + (float)(d * d); }
    // xor-tree == numpy association: ((r0+r1)+(r2+r3))+((r4+r5)+(r6+r7)), then (B0+B1)+(B2+B3)
#pragma unroll
    for (int m = 1; m <= 16; m <<= 1) r = r + __shfl_xor(r, m);
    if (l32 == 0) *dst = r;
}

// ---------- pass-1 GEMM: 64 tokens x 4096 codes per block, no barriers in K-loop ----------
__global__ __launch_bounds__(512, 2) void vq_gemm(
    const unsigned char* __restrict__ Xim, const unsigned char* __restrict__ Eim,
    float* __restrict__ vbuf, int* __restrict__ ibuf)
{
    __shared__ unsigned int smemU[32768];  // 128 KiB: X fragment lines
    const int tid = threadIdx.x;
    const int lane = tid & 63, w = tid >> 6;
    const int hi5 = lane >> 5, l31 = lane & 31;
    const int tb = blockIdx.x >> 1, q = blockIdx.x & 1;

    // load X block image (128KB) linearly into LDS
    {
        const unsigned char* src = Xim + (size_t)tb * 131072;
#pragma unroll
        for (int c = 0; c < 16; ++c) {
            int off = (c * 512 + tid) * 16;
            int doff = (c * 512 + w * 64) * 16;  // wave-uniform dest base
            __builtin_amdgcn_global_load_lds((const unsigned int*)(src + off),
                                             (unsigned int*)((unsigned char*)smemU + doff), 16, 0, 0);
        }
    }
    __syncthreads();

    float v0[2], v1[2]; int i0[2], i1[2];
#pragma unroll
    for (int tf = 0; tf < 2; ++tf) { v0[tf] = -1e30f; v1[tf] = -1e30f; i0[tf] = 0; i1[tf] = 1; }

    const unsigned char* smemB = (const unsigned char*)smemU;

    for (int ck = 0; ck < 4; ++ck) {
        const int cb0 = q * 128 + ck * 32 + w * 4;   // code-block base (32-code units)
        f32x16 acc[4][2] = {};

        bf16x8 A0[4], A1[4];
#pragma unroll
        for (int cf = 0; cf < 4; ++cf)
            A0[cf] = *(const bf16x8*)(Eim + (size_t)((cb0 + cf) * 32 + 0) * 1024 + lane * 16);

#pragma unroll
        for (int s = 0; s < 32; ++s) {
            const bf16x8* Ac = (s & 1) ? A1 : A0;
            bf16x8*       An = (s & 1) ? A0 : A1;
            if (s < 31) {
#pragma unroll
                for (int cf = 0; cf < 4; ++cf)
                    An[cf] = *(const bf16x8*)(Eim + (size_t)((cb0 + cf) * 32 + (s + 1)) * 1024 + lane * 16);
            }
            bf16x8 Bh[2], Bl[2];
#pragma unroll
            for (int tf = 0; tf < 2; ++tf) {
                int lb = ((s * 2 + tf) * 2) * 1024 + lane * 16;
                Bh[tf] = *(const bf16x8*)(smemB + lb);
                Bl[tf] = *(const bf16x8*)(smemB + lb + 1024);
            }
#pragma unroll
            for (int cf = 0; cf < 4; ++cf) {
#pragma unroll
                for (int tf = 0; tf < 2; ++tf) {
                    acc[cf][tf] = __builtin_amdgcn_mfma_f32_32x32x16_bf16(Ac[cf], Bh[tf], acc[cf][tf], 0, 0, 0);
                    acc[cf][tf] = __builtin_amdgcn_mfma_f32_32x32x16_bf16(Ac[cf], Bl[tf], acc[cf][tf], 0, 0, 0);
                }
            }
        }

        // top-2 insert, ascending code order (strict > keeps lowest index on ties)
        const int code_base = q * 4096 + ck * 1024 + w * 128;
#pragma unroll
        for (int tf = 0; tf < 2; ++tf) {
#pragma unroll
            for (int cf = 0; cf < 4; ++cf) {
#pragma unroll
                for (int g = 0; g < 16; ++g) {
                    float v = acc[cf][tf][g];
                    int code = code_base + cf * 32 + ((g & 3) + 8 * (g >> 2) + 4 * hi5);
                    if (v > v0[tf])      { v1[tf] = v0[tf]; i1[tf] = i0[tf]; v0[tf] = v; i0[tf] = code; }
                    else if (v > v1[tf]) { v1[tf] = v; i1[tf] = code; }
                }
            }
        }
    }

#pragma unroll
    for (int tf = 0; tf < 2; ++tf) {
        int token = tb * 64 + tf * 32 + l31;
        int slot  = q * 16 + w * 2 + hi5;
        size_t base = (size_t)token * 64 + slot * 2;
        vbuf[base] = v0[tf];     ibuf[base] = i0[tf];
        vbuf[base + 1] = v1[tf]; ibuf[base + 1] = i1[tf];
    }
}

// ---------- refine: one wave per token, exact f32-grid reconstruction ----------
__global__ __launch_bounds__(256) void vq_refine(
    const float* __restrict__ X, const float* __restrict__ E,
    const float* __restrict__ vbuf, const int* __restrict__ ibuf,
    const float* __restrict__ sx, const float* __restrict__ se,
    float* __restrict__ out_idx)
{
    int t = threadIdx.x;
    int n = blockIdx.x * 4 + (t >> 6);
    int lane = t & 63;

    float v = vbuf[(size_t)n * 64 + lane];
    int   ci = ibuf[(size_t)n * 64 + lane];
    float b0 = v;
#pragma unroll
    for (int m = 1; m <= 32; m <<= 1) b0 = fmaxf(b0, __shfl_xor(b0, m));

    unsigned long long mask = __ballot(v >= b0 - 1.2e-4f);

    const float* xr = X + (size_t)n * D_DIM;
    float4 xa = ((const float4*)xr)[lane * 2];
    float4 xb = ((const float4*)xr)[lane * 2 + 1];
    float sxn = sx[n];

    float bd = 1e30f; int bi = 2147483647;
    while (mask) {
        int b = (int)__builtin_ctzll(mask);
        mask &= mask - 1;
        int idx = __shfl(ci, b);
        const float* er = E + (size_t)idx * D_DIM;
        float4 ea = ((const float4*)er)[lane * 2];
        float4 eb = ((const float4*)er)[lane * 2 + 1];
        double p = (double)xa.x * ea.x + (double)xa.y * ea.y + (double)xa.z * ea.z + (double)xa.w * ea.w
                 + (double)xb.x * eb.x + (double)xb.y * eb.y + (double)xb.z * eb.z + (double)xb.w * eb.w;
#pragma unroll
        for (int m = 1; m <= 32; m <<= 1) p = p + __shfl_xor(p, m);
        float M = (float)p;
        float S = sxn + se[idx];
        float d = S - 2.0f * M;
        if (d < bd || (d == bd && idx < bi)) { bd = d; bi = idx; }
    }
    if (lane == 0) out_idx[n] = (float)bi;
}

// ---------- gather + loss ----------
__global__ __launch_bounds__(256) void vq_gather(
    const float* __restrict__ X, const float* __restrict__ E,
    const float* __restrict__ idxf, float* __restrict__ outq, float* __restrict__ outl)
{
    const int t = threadIdx.x;
    const int h = t >> 7, tt = t & 127;
    const int n = blockIdx.x * 2 + h;
    const int idx = (int)idxf[n];
    const float4* xr = (const float4*)(X + (size_t)n * D_DIM);
    const float4* er = (const float4*)(E + (size_t)idx * D_DIM);
    float4* qr = (float4*)(outq + (size_t)n * D_DIM);
    float4 x = xr[tt], e = er[tt];
    float4 dl; dl.x = e.x - x.x; dl.y = e.y - x.y; dl.z = e.z - x.z; dl.w = e.w - x.w;
    float4 qv; qv.x = x.x + dl.x; qv.y = x.y + dl.y; qv.z = x.z + dl.z; qv.w = x.w + dl.w;
    qr[tt] = qv;
    float s = dl.x * dl.x + dl.y * dl.y + dl.z * dl.z + dl.w * dl.w;
#pragma unroll
    for (int off = 32; off > 0; off >>= 1) s += __shfl_down(s, off, 64);
    __shared__ float red[4];
    if ((t & 63) == 0) red[t >> 6] = s;
    __syncthreads();
    if (tt == 0) {
        float m = (red[h * 2] + red[h * 2 + 1]) * (1.0f / (float)D_DIM);
        outl[n] = m + 0.25f * m;
    }
}

// ---------- fallback (proven round-2 path) ----------
__global__ __launch_bounds__(512) void vq_argmin_fb(
    const float* __restrict__ X, const float* __restrict__ E, float* __restrict__ out_idx)
{
    __shared__ __align__(16) unsigned char smem[48 * 1024];
    float4* Xs = (float4*)smem;
    float4* Es = (float4*)(smem + 16 * 1024);
    float*  cv = (float*)smem;
    int*    ci = (int*)(smem + 16 * 1024);
    const int t = threadIdx.x, tc = t & 31, tr = t >> 5;
    const int tok0 = blockIdx.x * 64;
    const float4* Xg = (const float4*)X;
    const float4* Eg = (const float4*)E;
    float v0[4], v1[4]; int i0[4], i1[4];
#pragma unroll
    for (int i = 0; i < 4; ++i) { v0[i] = -1e30f; v1[i] = -1e30f; i0[i] = 0; i1[i] = 1; }
    for (int kt = 0; kt < K_CODES / 128; ++kt) {
        float acc[4][4];
#pragma unroll
        for (int i = 0; i < 4; ++i)
#pragma unroll
            for (int j = 0; j < 4; ++j) acc[i][j] = 0.f;
        for (int dc = 0; dc < 8; ++dc) {
            __syncthreads();
#pragma unroll
            for (int s = 0; s < 2; ++s) {
                int id = t + s * 512; int rr = id >> 4, m = id & 15;
                Xs[rr * 16 + ((m + (rr >> 2)) & 15)] = Xg[(size_t)(tok0 + rr) * 128 + dc * 16 + m];
            }
#pragma unroll
            for (int s = 0; s < 4; ++s) {
                int id = t + s * 512; int rr = id >> 4, m = id & 15;
                Es[rr * 16 + ((m + (rr >> 2)) & 15)] = Eg[(size_t)(kt * 128 + rr) * 128 + dc * 16 + m];
            }
            __syncthreads();
#pragma unroll
            for (int dd4 = 0; dd4 < 16; ++dd4) {
                float4 xv[4], ev[4];
#pragma unroll
                for (int i = 0; i < 4; ++i) xv[i] = Xs[(4 * tr + i) * 16 + ((dd4 + tr) & 15)];
#pragma unroll
                for (int j = 0; j < 4; ++j) ev[j] = Es[(4 * tc + j) * 16 + ((dd4 + tc) & 15)];
#pragma unroll
                for (int i = 0; i < 4; ++i)
#pragma unroll
                    for (int j = 0; j < 4; ++j)
                        acc[i][j] += xv[i].x * ev[j].x + xv[i].y * ev[j].y + xv[i].z * ev[j].z + xv[i].w * ev[j].w;
            }
        }
#pragma unroll
        for (int i = 0; i < 4; ++i)
#pragma unroll
            for (int j = 0; j < 4; ++j) {
                float v = acc[i][j]; int idx = kt * 128 + 4 * tc + j;
                if (v > v0[i])      { v1[i] = v0[i]; i1[i] = i0[i]; v0[i] = v; i0[i] = idx; }
                else if (v > v1[i]) { v1[i] = v; i1[i] = idx; }
            }
    }
    __syncthreads();
#pragma unroll
    for (int i = 0; i < 4; ++i) {
        int row = 4 * tr + i;
        cv[row * 64 + 2 * tc] = v0[i];     ci[row * 64 + 2 * tc] = i0[i];
        cv[row * 64 + 2 * tc + 1] = v1[i]; ci[row * 64 + 2 * tc + 1] = i1[i];
    }
    __syncthreads();
    if (t < 64) {
        const int row = t;
        float b0 = -1e30f;
        for (int s = 0; s < 64; ++s) b0 = fmaxf(b0, cv[row * 64 + s]);
        const float* xr = X + (size_t)(tok0 + row) * D_DIM;
        const float sumx2 = np_pairwise_sq(xr);
        float bd = 1e30f; int bi = 0x7fffffff;
        for (int s = 0; s < 64; ++s) {
            float v = cv[row * 64 + s];
            if (v < b0 - 1.0e-4f) continue;
            int idx = ci[row * 64 + s];
            const float* er = E + (size_t)idx * D_DIM;
            double acc = 0.0;
            for (int d0 = 0; d0 < D_DIM; ++d0) acc += (double)xr[d0] * (double)er[d0];
            float M = (float)acc;
            float se2 = np_pairwise_sq(er);
            float S = sumx2 + se2;
            float d = S - 2.0f * M;
            if (d < bd || (d == bd && idx < bi)) { bd = d; bi = idx; }
        }
        out_idx[tok0 + row] = (float)bi;
    }
}

extern "C" void kernel_launch(void* const* d_in, const int* in_sizes, int n_in,
                              void* d_out, int out_size, void* d_ws, size_t ws_size,
                              hipStream_t stream) {
    const float* X = (const float*)d_in[0];
    const float* E = (const float*)d_in[1];
    float* out  = (float*)d_out;
    float* outq = out;
    float* outl = out + (size_t)N_TOK * D_DIM;
    float* outi = outl + N_TOK;

    const size_t WS_NEED = 54525952;
    if (ws_size >= WS_NEED) {
        unsigned char* ws = (unsigned char*)d_ws;
        unsigned char* Xim = ws;                        // 32MB
        unsigned char* Eim = ws + 33554432;             // 8MB
        float* vbuf = (float*)(ws + 41943040);          // 4MB
        int*   ibuf = (int*)(ws + 46137344);            // 4MB
        float* sx   = (float*)(ws + 50331648);          // 64KB
        float* se   = (float*)(ws + 50397184);          // 32KB
        vq_convert<<<6144, 256, 0, stream>>>(X, E, Xim, Eim);
        vq_rowsq<<<3072, 256, 0, stream>>>(X, E, sx, se);
        vq_gemm<<<512, 512, 0, stream>>>(Xim, Eim, vbuf, ibuf);
        vq_refine<<<4096, 256, 0, stream>>>(X, E, vbuf, ibuf, sx, se, outi);
    } else {
        vq_argmin_fb<<<N_TOK / 64, 512, 0, stream>>>(X, E, outi);
    }
    vq_gather<<<8192, 256, 0, stream>>>(X, E, outi, outq, outl);
}

// Round 5
// 334.609 us; speedup vs baseline: 25.0300x; 2.2193x over previous
//
#include <hip/hip_runtime.h>

// VQ-VAE vector quantizer, MI355X. N=16384 tokens, D=512, K=8192 codes, f32.
// out0: quantized_st [N*D], out1: vq_loss [N], out2: encoding_inds [N] (as float)
//
// Pass-1: dot(x,e) ~ eh*(xh+xl) via MFMA (err ~2e-6 << tie window). E streamed
// global->reg as fragment lines (no barriers in K-loop); X resident in LDS full-D.
// Per-wave tile 64 codes x 64 tokens (acc=64 regs) to avoid scratch spills.
// Pass-2: exact f32-grid reconstruction (numpy-pairwise sums, f64->f32 dot),
// lowest-index tie-break. Window 1.2e-4 on approx dot.

#define D_DIM   512
#define K_CODES 8192
#define N_TOK   16384

typedef short bf16x8 __attribute__((ext_vector_type(8)));
typedef float f32x16 __attribute__((ext_vector_type(16)));

__device__ __forceinline__ unsigned short f2bf(float x) {
    unsigned u = __float_as_uint(x);
    return (unsigned short)((u + 0x7fffu + ((u >> 16) & 1u)) >> 16);
}

// exact numpy pairwise sum of squares over 512 f32 (serial-thread version, fallback path)
__device__ __forceinline__ float np_pairwise_sq(const float* __restrict__ a) {
    float blk[4];
#pragma unroll
    for (int b = 0; b < 4; ++b) {
        const float* p = a + b * 128;
        float r[8];
#pragma unroll
        for (int j = 0; j < 8; ++j) { double d = (double)p[j]; r[j] = (float)(d * d); }
        for (int i = 8; i < 128; i += 8) {
#pragma unroll
            for (int j = 0; j < 8; ++j) { double d = (double)p[i + j]; r[j] = r[j] + (float)(d * d); }
        }
        blk[b] = ((r[0] + r[1]) + (r[2] + r[3])) + ((r[4] + r[5]) + (r[6] + r[7]));
    }
    return (blk[0] + blk[1]) + (blk[2] + blk[3]);
}

// ---------- convert: build fragment-line images ----------
// Ximg: [tb 256][line2 64=(s*2+tf)][fmt 2][lane 64][16B]  (128KB per tb, 32MB)
// Eimg: [cb 256][s 32][lane 64][16B]                      (hi only, 8MB)
__global__ __launch_bounds__(256) void vq_convert(
    const float* __restrict__ X, const float* __restrict__ E,
    unsigned char* __restrict__ Xim, unsigned char* __restrict__ Eim)
{
    int tid = blockIdx.x * 256 + threadIdx.x;
    if (tid < 1048576) {  // X path
        int tb = tid >> 12, rem = tid & 4095;
        int line2 = rem >> 6, lane = rem & 63;
        int s = line2 >> 1, tf = line2 & 1;
        int hi5 = lane >> 5, t31 = lane & 31;
        int token = tb * 64 + tf * 32 + t31;
        int d0 = s * 16 + hi5 * 8;
        const float* p = X + (size_t)token * D_DIM + d0;
        unsigned h[8], l[8];
#pragma unroll
        for (int j = 0; j < 8; ++j) {
            float x = p[j];
            unsigned short hh = f2bf(x);
            float hf = __uint_as_float((unsigned)hh << 16);
            unsigned short ll = f2bf(x - hf);
            h[j] = hh; l[j] = ll;
        }
        uint4 hv = make_uint4(h[0]|(h[1]<<16), h[2]|(h[3]<<16), h[4]|(h[5]<<16), h[6]|(h[7]<<16));
        uint4 lv = make_uint4(l[0]|(l[1]<<16), l[2]|(l[3]<<16), l[4]|(l[5]<<16), l[6]|(l[7]<<16));
        size_t base = (size_t)tb * 131072 + (size_t)(line2 * 2) * 1024 + (size_t)lane * 16;
        *(uint4*)(Xim + base) = hv;
        *(uint4*)(Xim + base + 1024) = lv;
    } else if (tid < 1572864) {  // E path (hi only)
        int id2 = tid - 1048576;
        int cb = id2 >> 11, rem = id2 & 2047;
        int s = rem >> 6, lane = rem & 63;
        int hi5 = lane >> 5, c31 = lane & 31;
        int code = cb * 32 + c31;
        int d0 = s * 16 + hi5 * 8;
        const float* p = E + (size_t)code * D_DIM + d0;
        unsigned h[8];
#pragma unroll
        for (int j = 0; j < 8; ++j) h[j] = f2bf(p[j]);
        uint4 hv = make_uint4(h[0]|(h[1]<<16), h[2]|(h[3]<<16), h[4]|(h[5]<<16), h[6]|(h[7]<<16));
        *(uint4*)(Eim + (size_t)cb * 32768 + (size_t)s * 1024 + (size_t)lane * 16) = hv;
    }
}

// ---------- rowsq: exact numpy-pairwise sum of squares, one 32-lane group per row ----------
__global__ __launch_bounds__(256) void vq_rowsq(
    const float* __restrict__ X, const float* __restrict__ E,
    float* __restrict__ sx, float* __restrict__ se)
{
    int t = threadIdx.x;
    int wv = blockIdx.x * 4 + (t >> 6);
    int sub = (t >> 5) & 1, l32 = t & 31;
    int row = wv * 2 + sub;
    const float* p;
    float* dst;
    if (row < N_TOK) { p = X + (size_t)row * D_DIM; dst = sx + row; }
    else if (row < N_TOK + K_CODES) { p = E + (size_t)(row - N_TOK) * D_DIM; dst = se + (row - N_TOK); }
    else return;
    int b = l32 >> 3, rr = l32 & 7;
    const float* q = p + b * 128 + rr;
    double d0 = (double)q[0];
    float r = (float)(d0 * d0);
#pragma unroll
    for (int i = 1; i < 16; ++i) { double d = (double)q[8 * i]; r = r + (float)(d * d); }
#pragma unroll
    for (int m = 1; m <= 16; m <<= 1) r = r + __shfl_xor(r, m);
    if (l32 == 0) *dst = r;
}

// ---------- pass-1 GEMM: block = 512 codes x 64 tokens slice of the q-half ----------
// Grid 512 = 256 tb x 2 q, XCD-pinned: xcd=bid&7 owns one q and 64 contiguous tb
// so the per-XCD E working set is its 4MB q-half (L2-resident).
__global__ __launch_bounds__(512, 2) void vq_gemm(
    const unsigned char* __restrict__ Xim, const unsigned char* __restrict__ Eim,
    float* __restrict__ vbuf, int* __restrict__ ibuf)
{
    __shared__ unsigned int smemU[32768];  // 128 KiB: X fragment lines
    const int tid = threadIdx.x;
    const int lane = tid & 63, w = tid >> 6;
    const int hi5 = lane >> 5, l31 = lane & 31;

    const int bid  = blockIdx.x;
    const int xcd  = bid & 7, slot = bid >> 3;   // slot 0..63
    const int q    = xcd >> 2;
    const int tb   = (xcd & 3) * 64 + slot;

    // stage X block image (128 KiB) linearly into LDS
    {
        const unsigned char* src = Xim + (size_t)tb * 131072;
#pragma unroll
        for (int c = 0; c < 16; ++c) {
            int off  = (c * 512 + tid) * 16;
            int doff = (c * 512 + w * 64) * 16;   // wave-uniform dest base
            __builtin_amdgcn_global_load_lds((const unsigned int*)(src + off),
                                             (unsigned int*)((unsigned char*)smemU + doff), 16, 0, 0);
        }
    }
    __syncthreads();

    const unsigned char* smemB = (const unsigned char*)smemU;

    float v0[2], v1[2]; int i0[2], i1[2];
    v0[0] = v0[1] = -1e30f; v1[0] = v1[1] = -1e30f;
    i0[0] = i0[1] = 0; i1[0] = i1[1] = 1;

    for (int ck = 0; ck < 8; ++ck) {
        const int cb0 = q * 128 + ck * 16 + w * 2;           // 32-code block units
        const unsigned char* Abase = Eim + (size_t)cb0 * 32768;

        f32x16 acc00 = {}, acc01 = {}, acc10 = {}, acc11 = {};  // [cf][tf]

        // preload s=0 A-frags (cf=0,1)
        bf16x8 Aa0 = *(const bf16x8*)(Abase +           (size_t)lane * 16);
        bf16x8 Aa1 = *(const bf16x8*)(Abase + 32768 +   (size_t)lane * 16);
        bf16x8 Ab0, Ab1;

#pragma unroll 1
        for (int s2 = 0; s2 < 16; ++s2) {
            const int se_ = 2 * s2, so_ = 2 * s2 + 1, sn_ = (2 * s2 + 2) & 31;

            // prefetch odd-step A
            Ab0 = *(const bf16x8*)(Abase +         (size_t)so_ * 1024 + (size_t)lane * 16);
            Ab1 = *(const bf16x8*)(Abase + 32768 + (size_t)so_ * 1024 + (size_t)lane * 16);

            // even step: B frags from LDS, 8 MFMA with Aa
            {
                int lb0 = ((se_ * 2 + 0) * 2) * 1024 + lane * 16;
                int lb1 = ((se_ * 2 + 1) * 2) * 1024 + lane * 16;
                bf16x8 Bh0 = *(const bf16x8*)(smemB + lb0);
                bf16x8 Bl0 = *(const bf16x8*)(smemB + lb0 + 1024);
                bf16x8 Bh1 = *(const bf16x8*)(smemB + lb1);
                bf16x8 Bl1 = *(const bf16x8*)(smemB + lb1 + 1024);
                acc00 = __builtin_amdgcn_mfma_f32_32x32x16_bf16(Aa0, Bh0, acc00, 0, 0, 0);
                acc00 = __builtin_amdgcn_mfma_f32_32x32x16_bf16(Aa0, Bl0, acc00, 0, 0, 0);
                acc01 = __builtin_amdgcn_mfma_f32_32x32x16_bf16(Aa0, Bh1, acc01, 0, 0, 0);
                acc01 = __builtin_amdgcn_mfma_f32_32x32x16_bf16(Aa0, Bl1, acc01, 0, 0, 0);
                acc10 = __builtin_amdgcn_mfma_f32_32x32x16_bf16(Aa1, Bh0, acc10, 0, 0, 0);
                acc10 = __builtin_amdgcn_mfma_f32_32x32x16_bf16(Aa1, Bl0, acc10, 0, 0, 0);
                acc11 = __builtin_amdgcn_mfma_f32_32x32x16_bf16(Aa1, Bh1, acc11, 0, 0, 0);
                acc11 = __builtin_amdgcn_mfma_f32_32x32x16_bf16(Aa1, Bl1, acc11, 0, 0, 0);
            }

            // prefetch next even-step A (wraps to s=0 on last iter; value unused, in-bounds)
            Aa0 = *(const bf16x8*)(Abase +         (size_t)sn_ * 1024 + (size_t)lane * 16);
            Aa1 = *(const bf16x8*)(Abase + 32768 + (size_t)sn_ * 1024 + (size_t)lane * 16);

            // odd step: 8 MFMA with Ab
            {
                int lb0 = ((so_ * 2 + 0) * 2) * 1024 + lane * 16;
                int lb1 = ((so_ * 2 + 1) * 2) * 1024 + lane * 16;
                bf16x8 Bh0 = *(const bf16x8*)(smemB + lb0);
                bf16x8 Bl0 = *(const bf16x8*)(smemB + lb0 + 1024);
                bf16x8 Bh1 = *(const bf16x8*)(smemB + lb1);
                bf16x8 Bl1 = *(const bf16x8*)(smemB + lb1 + 1024);
                acc00 = __builtin_amdgcn_mfma_f32_32x32x16_bf16(Ab0, Bh0, acc00, 0, 0, 0);
                acc00 = __builtin_amdgcn_mfma_f32_32x32x16_bf16(Ab0, Bl0, acc00, 0, 0, 0);
                acc01 = __builtin_amdgcn_mfma_f32_32x32x16_bf16(Ab0, Bh1, acc01, 0, 0, 0);
                acc01 = __builtin_amdgcn_mfma_f32_32x32x16_bf16(Ab0, Bl1, acc01, 0, 0, 0);
                acc10 = __builtin_amdgcn_mfma_f32_32x32x16_bf16(Ab1, Bh0, acc10, 0, 0, 0);
                acc10 = __builtin_amdgcn_mfma_f32_32x32x16_bf16(Ab1, Bl0, acc10, 0, 0, 0);
                acc11 = __builtin_amdgcn_mfma_f32_32x32x16_bf16(Ab1, Bh1, acc11, 0, 0, 0);
                acc11 = __builtin_amdgcn_mfma_f32_32x32x16_bf16(Ab1, Bl1, acc11, 0, 0, 0);
            }
        }

        // top-2 insert, ascending code order (strict > keeps lowest index on ties)
#pragma unroll
        for (int g = 0; g < 16; ++g) {
            int code = (cb0 + 0) * 32 + ((g & 3) + 8 * (g >> 2) + 4 * hi5);
            float v = acc00[g];
            if (v > v0[0])      { v1[0] = v0[0]; i1[0] = i0[0]; v0[0] = v; i0[0] = code; }
            else if (v > v1[0]) { v1[0] = v; i1[0] = code; }
            v = acc01[g];
            if (v > v0[1])      { v1[1] = v0[1]; i1[1] = i0[1]; v0[1] = v; i0[1] = code; }
            else if (v > v1[1]) { v1[1] = v; i1[1] = code; }
        }
#pragma unroll
        for (int g = 0; g < 16; ++g) {
            int code = (cb0 + 1) * 32 + ((g & 3) + 8 * (g >> 2) + 4 * hi5);
            float v = acc10[g];
            if (v > v0[0])      { v1[0] = v0[0]; i1[0] = i0[0]; v0[0] = v; i0[0] = code; }
            else if (v > v1[0]) { v1[0] = v; i1[0] = code; }
            v = acc11[g];
            if (v > v0[1])      { v1[1] = v0[1]; i1[1] = i0[1]; v0[1] = v; i0[1] = code; }
            else if (v > v1[1]) { v1[1] = v; i1[1] = code; }
        }
    }

#pragma unroll
    for (int tf = 0; tf < 2; ++tf) {
        int token = tb * 64 + tf * 32 + l31;
        int slot2 = q * 16 + w * 2 + hi5;
        size_t base = (size_t)token * 64 + slot2 * 2;
        vbuf[base] = v0[tf];     ibuf[base] = i0[tf];
        vbuf[base + 1] = v1[tf]; ibuf[base + 1] = i1[tf];
    }
}

// ---------- refine: one wave per token, exact f32-grid reconstruction ----------
__global__ __launch_bounds__(256) void vq_refine(
    const float* __restrict__ X, const float* __restrict__ E,
    const float* __restrict__ vbuf, const int* __restrict__ ibuf,
    const float* __restrict__ sx, const float* __restrict__ se,
    float* __restrict__ out_idx)
{
    int t = threadIdx.x;
    int n = blockIdx.x * 4 + (t >> 6);
    int lane = t & 63;

    float v = vbuf[(size_t)n * 64 + lane];
    int   ci = ibuf[(size_t)n * 64 + lane];
    float b0 = v;
#pragma unroll
    for (int m = 1; m <= 32; m <<= 1) b0 = fmaxf(b0, __shfl_xor(b0, m));

    unsigned long long mask = __ballot(v >= b0 - 1.2e-4f);

    const float* xr = X + (size_t)n * D_DIM;
    float4 xa = ((const float4*)xr)[lane * 2];
    float4 xb = ((const float4*)xr)[lane * 2 + 1];
    float sxn = sx[n];

    float bd = 1e30f; int bi = 2147483647;
    while (mask) {
        int b = (int)__builtin_ctzll(mask);
        mask &= mask - 1;
        int idx = __shfl(ci, b);
        const float* er = E + (size_t)idx * D_DIM;
        float4 ea = ((const float4*)er)[lane * 2];
        float4 eb = ((const float4*)er)[lane * 2 + 1];
        double p = (double)xa.x * ea.x + (double)xa.y * ea.y + (double)xa.z * ea.z + (double)xa.w * ea.w
                 + (double)xb.x * eb.x + (double)xb.y * eb.y + (double)xb.z * eb.z + (double)xb.w * eb.w;
#pragma unroll
        for (int m = 1; m <= 32; m <<= 1) p = p + __shfl_xor(p, m);
        float M = (float)p;
        float S = sxn + se[idx];
        float d = S - 2.0f * M;
        if (d < bd || (d == bd && idx < bi)) { bd = d; bi = idx; }
    }
    if (lane == 0) out_idx[n] = (float)bi;
}

// ---------- gather + loss ----------
__global__ __launch_bounds__(256) void vq_gather(
    const float* __restrict__ X, const float* __restrict__ E,
    const float* __restrict__ idxf, float* __restrict__ outq, float* __restrict__ outl)
{
    const int t = threadIdx.x;
    const int h = t >> 7, tt = t & 127;
    const int n = blockIdx.x * 2 + h;
    const int idx = (int)idxf[n];
    const float4* xr = (const float4*)(X + (size_t)n * D_DIM);
    const float4* er = (const float4*)(E + (size_t)idx * D_DIM);
    float4* qr = (float4*)(outq + (size_t)n * D_DIM);
    float4 x = xr[tt], e = er[tt];
    float4 dl; dl.x = e.x - x.x; dl.y = e.y - x.y; dl.z = e.z - x.z; dl.w = e.w - x.w;
    float4 qv; qv.x = x.x + dl.x; qv.y = x.y + dl.y; qv.z = x.z + dl.z; qv.w = x.w + dl.w;
    qr[tt] = qv;
    float s = dl.x * dl.x + dl.y * dl.y + dl.z * dl.z + dl.w * dl.w;
#pragma unroll
    for (int off = 32; off > 0; off >>= 1) s += __shfl_down(s, off, 64);
    __shared__ float red[4];
    if ((t & 63) == 0) red[t >> 6] = s;
    __syncthreads();
    if (tt == 0) {
        float m = (red[h * 2] + red[h * 2 + 1]) * (1.0f / (float)D_DIM);
        outl[n] = m + 0.25f * m;
    }
}

// ---------- fallback (proven round-2 path) ----------
__global__ __launch_bounds__(512) void vq_argmin_fb(
    const float* __restrict__ X, const float* __restrict__ E, float* __restrict__ out_idx)
{
    __shared__ __align__(16) unsigned char smem[48 * 1024];
    float4* Xs = (float4*)smem;
    float4* Es = (float4*)(smem + 16 * 1024);
    float*  cv = (float*)smem;
    int*    ci = (int*)(smem + 16 * 1024);
    const int t = threadIdx.x, tc = t & 31, tr = t >> 5;
    const int tok0 = blockIdx.x * 64;
    const float4* Xg = (const float4*)X;
    const float4* Eg = (const float4*)E;
    float v0[4], v1[4]; int i0[4], i1[4];
#pragma unroll
    for (int i = 0; i < 4; ++i) { v0[i] = -1e30f; v1[i] = -1e30f; i0[i] = 0; i1[i] = 1; }
    for (int kt = 0; kt < K_CODES / 128; ++kt) {
        float acc[4][4];
#pragma unroll
        for (int i = 0; i < 4; ++i)
#pragma unroll
            for (int j = 0; j < 4; ++j) acc[i][j] = 0.f;
        for (int dc = 0; dc < 8; ++dc) {
            __syncthreads();
#pragma unroll
            for (int s = 0; s < 2; ++s) {
                int id = t + s * 512; int rr = id >> 4, m = id & 15;
                Xs[rr * 16 + ((m + (rr >> 2)) & 15)] = Xg[(size_t)(tok0 + rr) * 128 + dc * 16 + m];
            }
#pragma unroll
            for (int s = 0; s < 4; ++s) {
                int id = t + s * 512; int rr = id >> 4, m = id & 15;
                Es[rr * 16 + ((m + (rr >> 2)) & 15)] = Eg[(size_t)(kt * 128 + rr) * 128 + dc * 16 + m];
            }
            __syncthreads();
#pragma unroll
            for (int dd4 = 0; dd4 < 16; ++dd4) {
                float4 xv[4], ev[4];
#pragma unroll
                for (int i = 0; i < 4; ++i) xv[i] = Xs[(4 * tr + i) * 16 + ((dd4 + tr) & 15)];
#pragma unroll
                for (int j = 0; j < 4; ++j) ev[j] = Es[(4 * tc + j) * 16 + ((dd4 + tc) & 15)];
#pragma unroll
                for (int i = 0; i < 4; ++i)
#pragma unroll
                    for (int j = 0; j < 4; ++j)
                        acc[i][j] += xv[i].x * ev[j].x + xv[i].y * ev[j].y + xv[i].z * ev[j].z + xv[i].w * ev[j].w;
            }
        }
#pragma unroll
        for (int i = 0; i < 4; ++i)
#pragma unroll
            for (int j = 0; j < 4; ++j) {
                float v = acc[i][j]; int idx = kt * 128 + 4 * tc + j;
                if (v > v0[i])      { v1[i] = v0[i]; i1[i] = i0[i]; v0[i] = v; i0[i] = idx; }
                else if (v > v1[i]) { v1[i] = v; i1[i] = idx; }
            }
    }
    __syncthreads();
#pragma unroll
    for (int i = 0; i < 4; ++i) {
        int row = 4 * tr + i;
        cv[row * 64 + 2 * tc] = v0[i];     ci[row * 64 + 2 * tc] = i0[i];
        cv[row * 64 + 2 * tc + 1] = v1[i]; ci[row * 64 + 2 * tc + 1] = i1[i];
    }
    __syncthreads();
    if (t < 64) {
        const int row = t;
        float b0 = -1e30f;
        for (int s = 0; s < 64; ++s) b0 = fmaxf(b0, cv[row * 64 + s]);
        const float* xr = X + (size_t)(tok0 + row) * D_DIM;
        const float sumx2 = np_pairwise_sq(xr);
        float bd = 1e30f; int bi = 0x7fffffff;
        for (int s = 0; s < 64; ++s) {
            float v = cv[row * 64 + s];
            if (v < b0 - 1.0e-4f) continue;
            int idx = ci[row * 64 + s];
            const float* er = E + (size_t)idx * D_DIM;
            double acc = 0.0;
            for (int d0 = 0; d0 < D_DIM; ++d0) acc += (double)xr[d0] * (double)er[d0];
            float M = (float)acc;
            float se2 = np_pairwise_sq(er);
            float S = sumx2 + se2;
            float d = S - 2.0f * M;
            if (d < bd || (d == bd && idx < bi)) { bd = d; bi = idx; }
        }
        out_idx[tok0 + row] = (float)bi;
    }
}

extern "C" void kernel_launch(void* const* d_in, const int* in_sizes, int n_in,
                              void* d_out, int out_size, void* d_ws, size_t ws_size,
                              hipStream_t stream) {
    const float* X = (const float*)d_in[0];
    const float* E = (const float*)d_in[1];
    float* out  = (float*)d_out;
    float* outq = out;
    float* outl = out + (size_t)N_TOK * D_DIM;
    float* outi = outl + N_TOK;

    const size_t WS_NEED = 54525952;
    if (ws_size >= WS_NEED) {
        unsigned char* ws = (unsigned char*)d_ws;
        unsigned char* Xim = ws;                        // 32MB
        unsigned char* Eim = ws + 33554432;             // 8MB
        float* vbuf = (float*)(ws + 41943040);          // 4MB
        int*   ibuf = (int*)(ws + 46137344);            // 4MB
        float* sx   = (float*)(ws + 50331648);          // 64KB
        float* se   = (float*)(ws + 50397184);          // 32KB
        vq_convert<<<6144, 256, 0, stream>>>(X, E, Xim, Eim);
        vq_rowsq<<<3072, 256, 0, stream>>>(X, E, sx, se);
        vq_gemm<<<512, 512, 0, stream>>>(Xim, Eim, vbuf, ibuf);
        vq_refine<<<4096, 256, 0, stream>>>(X, E, vbuf, ibuf, sx, se, outi);
    } else {
        vq_argmin_fb<<<N_TOK / 64, 512, 0, stream>>>(X, E, outi);
    }
    vq_gather<<<8192, 256, 0, stream>>>(X, E, outi, outq, outl);
}

// Round 6
// 219.488 us; speedup vs baseline: 38.1581x; 1.5245x over previous
//
#include <hip/hip_runtime.h>

// VQ-VAE vector quantizer, MI355X. N=16384 tokens, D=512, K=8192 codes, f32.
// out0: quantized_st [N*D], out1: vq_loss [N], out2: encoding_inds [N] (as float)
//
// Pass-1: rank codes by bf16 dot xh*eh via MFMA (err rms ~2.4e-6 << 1.2e-4 window).
// E streamed global->reg as fragment lines (no barriers in K-loop); X-hi resident in
// LDS (64KB -> 2 blocks/CU). MFMA dependency distance 4; A and B prefetched 1 step.
// Pass-2: exact f32-grid reconstruction (numpy-pairwise sums, f64->f32 dot),
// lowest-index tie-break, window 1.2e-4 on approx dot.

#define D_DIM   512
#define K_CODES 8192
#define N_TOK   16384

typedef short bf16x8 __attribute__((ext_vector_type(8)));
typedef float f32x16 __attribute__((ext_vector_type(16)));

__device__ __forceinline__ unsigned short f2bf(float x) {
    unsigned u = __float_as_uint(x);
    return (unsigned short)((u + 0x7fffu + ((u >> 16) & 1u)) >> 16);
}

// exact numpy pairwise sum of squares over 512 f32 (serial-thread version, fallback path)
__device__ __forceinline__ float np_pairwise_sq(const float* __restrict__ a) {
    float blk[4];
#pragma unroll
    for (int b = 0; b < 4; ++b) {
        const float* p = a + b * 128;
        float r[8];
#pragma unroll
        for (int j = 0; j < 8; ++j) { double d = (double)p[j]; r[j] = (float)(d * d); }
        for (int i = 8; i < 128; i += 8) {
#pragma unroll
            for (int j = 0; j < 8; ++j) { double d = (double)p[i + j]; r[j] = r[j] + (float)(d * d); }
        }
        blk[b] = ((r[0] + r[1]) + (r[2] + r[3])) + ((r[4] + r[5]) + (r[6] + r[7]));
    }
    return (blk[0] + blk[1]) + (blk[2] + blk[3]);
}

// ---------- convert: build bf16-hi fragment-line images ----------
// Ximg: [tb 256][line 64 = s*2+tf][lane 64][16B]  (64KB per tb, 16MB total)
// Eimg: [cb 256][s 32][lane 64][16B]              (8MB)
// lane = hi5*32 + (row&31); data = bf16x8 of row, d = s*16 + hi5*8 ..+7
__global__ __launch_bounds__(256) void vq_convert(
    const float* __restrict__ X, const float* __restrict__ E,
    unsigned char* __restrict__ Xim, unsigned char* __restrict__ Eim)
{
    int tid = blockIdx.x * 256 + threadIdx.x;
    if (tid < 1048576) {  // X path (hi only)
        int tb = tid >> 12, rem = tid & 4095;
        int line = rem >> 6, lane = rem & 63;
        int s = line >> 1, tf = line & 1;
        int hi5 = lane >> 5, t31 = lane & 31;
        int token = tb * 64 + tf * 32 + t31;
        int d0 = s * 16 + hi5 * 8;
        const float* p = X + (size_t)token * D_DIM + d0;
        unsigned h[8];
#pragma unroll
        for (int j = 0; j < 8; ++j) h[j] = f2bf(p[j]);
        uint4 hv = make_uint4(h[0]|(h[1]<<16), h[2]|(h[3]<<16), h[4]|(h[5]<<16), h[6]|(h[7]<<16));
        *(uint4*)(Xim + (size_t)tb * 65536 + (size_t)line * 1024 + (size_t)lane * 16) = hv;
    } else if (tid < 1572864) {  // E path (hi only)
        int id2 = tid - 1048576;
        int cb = id2 >> 11, rem = id2 & 2047;
        int s = rem >> 6, lane = rem & 63;
        int hi5 = lane >> 5, c31 = lane & 31;
        int code = cb * 32 + c31;
        int d0 = s * 16 + hi5 * 8;
        const float* p = E + (size_t)code * D_DIM + d0;
        unsigned h[8];
#pragma unroll
        for (int j = 0; j < 8; ++j) h[j] = f2bf(p[j]);
        uint4 hv = make_uint4(h[0]|(h[1]<<16), h[2]|(h[3]<<16), h[4]|(h[5]<<16), h[6]|(h[7]<<16));
        *(uint4*)(Eim + (size_t)cb * 32768 + (size_t)s * 1024 + (size_t)lane * 16) = hv;
    }
}

// ---------- rowsq: exact numpy-pairwise sum of squares, one 32-lane group per row ----------
__global__ __launch_bounds__(256) void vq_rowsq(
    const float* __restrict__ X, const float* __restrict__ E,
    float* __restrict__ sx, float* __restrict__ se)
{
    int t = threadIdx.x;
    int wv = blockIdx.x * 4 + (t >> 6);
    int sub = (t >> 5) & 1, l32 = t & 31;
    int row = wv * 2 + sub;
    const float* p;
    float* dst;
    if (row < N_TOK) { p = X + (size_t)row * D_DIM; dst = sx + row; }
    else if (row < N_TOK + K_CODES) { p = E + (size_t)(row - N_TOK) * D_DIM; dst = se + (row - N_TOK); }
    else return;
    int b = l32 >> 3, rr = l32 & 7;
    const float* q = p + b * 128 + rr;
    double d0 = (double)q[0];
    float r = (float)(d0 * d0);
#pragma unroll
    for (int i = 1; i < 16; ++i) { double d = (double)q[8 * i]; r = r + (float)(d * d); }
#pragma unroll
    for (int m = 1; m <= 16; m <<= 1) r = r + __shfl_xor(r, m);
    if (l32 == 0) *dst = r;
}

// ---------- pass-1 GEMM: block = 512 codes x 64 tokens slice of the q-half ----------
// Grid 512 = 256 tb x 2 q, XCD-pinned so each XCD's E working set is its 4MB q-half.
__global__ __launch_bounds__(512, 4) void vq_gemm(
    const unsigned char* __restrict__ Xim, const unsigned char* __restrict__ Eim,
    float* __restrict__ vbuf, int* __restrict__ ibuf)
{
    __shared__ unsigned int smemU[16384];  // 64 KiB: X-hi fragment lines
    const int tid = threadIdx.x;
    const int lane = tid & 63, w = tid >> 6;
    const int hi5 = lane >> 5, l31 = lane & 31;

    const int bid  = blockIdx.x;
    const int xcd  = bid & 7, slot = bid >> 3;   // slot 0..63
    const int q    = xcd >> 2;
    const int tb   = (xcd & 3) * 64 + slot;

    // stage X block image (64 KiB) linearly into LDS
    {
        const unsigned char* src = Xim + (size_t)tb * 65536;
#pragma unroll
        for (int c = 0; c < 8; ++c) {
            int off  = (c * 512 + tid) * 16;
            int doff = (c * 512 + w * 64) * 16;   // wave-uniform dest base
            __builtin_amdgcn_global_load_lds((const unsigned int*)(src + off),
                                             (unsigned int*)((unsigned char*)smemU + doff), 16, 0, 0);
        }
    }
    __syncthreads();

    const unsigned char* smemB = (const unsigned char*)smemU;

    float v0[2], v1[2]; int i0[2], i1[2];
    v0[0] = v0[1] = -1e30f; v1[0] = v1[1] = -1e30f;
    i0[0] = i0[1] = 0; i1[0] = i1[1] = 1;

#pragma unroll 1
    for (int ck = 0; ck < 8; ++ck) {
        const int cb0 = q * 128 + ck * 16 + w * 2;           // 32-code block units
        const unsigned char* Ab0p = Eim + (size_t)cb0 * 32768;
        const unsigned char* Ab1p = Ab0p + 32768;

        f32x16 acc00 = {}, acc01 = {}, acc10 = {}, acc11 = {};  // [cf][tf]

        // preload s=0 A-frags and B-frags
        bf16x8 A0a = *(const bf16x8*)(Ab0p + (size_t)lane * 16);
        bf16x8 A1a = *(const bf16x8*)(Ab1p + (size_t)lane * 16);
        bf16x8 B0a = *(const bf16x8*)(smemB + lane * 16);
        bf16x8 B1a = *(const bf16x8*)(smemB + 1024 + lane * 16);
        bf16x8 A0b, A1b, B0b, B1b;

#pragma unroll 1
        for (int s2 = 0; s2 < 16; ++s2) {
            const int so_ = 2 * s2 + 1, sn_ = (2 * s2 + 2) & 31;

            // prefetch odd-step A (global) and B (LDS)
            A0b = *(const bf16x8*)(Ab0p + (size_t)so_ * 1024 + (size_t)lane * 16);
            A1b = *(const bf16x8*)(Ab1p + (size_t)so_ * 1024 + (size_t)lane * 16);
            B0b = *(const bf16x8*)(smemB + (so_ * 2 + 0) * 1024 + lane * 16);
            B1b = *(const bf16x8*)(smemB + (so_ * 2 + 1) * 1024 + lane * 16);

            // even step: dependency distance 4
            acc00 = __builtin_amdgcn_mfma_f32_32x32x16_bf16(A0a, B0a, acc00, 0, 0, 0);
            acc10 = __builtin_amdgcn_mfma_f32_32x32x16_bf16(A1a, B0a, acc10, 0, 0, 0);
            acc01 = __builtin_amdgcn_mfma_f32_32x32x16_bf16(A0a, B1a, acc01, 0, 0, 0);
            acc11 = __builtin_amdgcn_mfma_f32_32x32x16_bf16(A1a, B1a, acc11, 0, 0, 0);

            // prefetch next even-step (wraps to s=0 on last iter; value unused, in-bounds)
            A0a = *(const bf16x8*)(Ab0p + (size_t)sn_ * 1024 + (size_t)lane * 16);
            A1a = *(const bf16x8*)(Ab1p + (size_t)sn_ * 1024 + (size_t)lane * 16);
            B0a = *(const bf16x8*)(smemB + (sn_ * 2 + 0) * 1024 + lane * 16);
            B1a = *(const bf16x8*)(smemB + (sn_ * 2 + 1) * 1024 + lane * 16);

            // odd step
            acc00 = __builtin_amdgcn_mfma_f32_32x32x16_bf16(A0b, B0b, acc00, 0, 0, 0);
            acc10 = __builtin_amdgcn_mfma_f32_32x32x16_bf16(A1b, B0b, acc10, 0, 0, 0);
            acc01 = __builtin_amdgcn_mfma_f32_32x32x16_bf16(A0b, B1b, acc01, 0, 0, 0);
            acc11 = __builtin_amdgcn_mfma_f32_32x32x16_bf16(A1b, B1b, acc11, 0, 0, 0);
        }

        // top-2 insert, ascending code order (strict > keeps lowest index on ties)
#pragma unroll
        for (int g = 0; g < 16; ++g) {
            int code = (cb0 + 0) * 32 + ((g & 3) + 8 * (g >> 2) + 4 * hi5);
            float v = acc00[g];
            if (v > v0[0])      { v1[0] = v0[0]; i1[0] = i0[0]; v0[0] = v; i0[0] = code; }
            else if (v > v1[0]) { v1[0] = v; i1[0] = code; }
            v = acc01[g];
            if (v > v0[1])      { v1[1] = v0[1]; i1[1] = i0[1]; v0[1] = v; i0[1] = code; }
            else if (v > v1[1]) { v1[1] = v; i1[1] = code; }
        }
#pragma unroll
        for (int g = 0; g < 16; ++g) {
            int code = (cb0 + 1) * 32 + ((g & 3) + 8 * (g >> 2) + 4 * hi5);
            float v = acc10[g];
            if (v > v0[0])      { v1[0] = v0[0]; i1[0] = i0[0]; v0[0] = v; i0[0] = code; }
            else if (v > v1[0]) { v1[0] = v; i1[0] = code; }
            v = acc11[g];
            if (v > v0[1])      { v1[1] = v0[1]; i1[1] = i0[1]; v0[1] = v; i0[1] = code; }
            else if (v > v1[1]) { v1[1] = v; i1[1] = code; }
        }
    }

#pragma unroll
    for (int tf = 0; tf < 2; ++tf) {
        int token = tb * 64 + tf * 32 + l31;
        int slot2 = q * 16 + w * 2 + hi5;
        size_t base = (size_t)token * 64 + slot2 * 2;
        vbuf[base] = v0[tf];     ibuf[base] = i0[tf];
        vbuf[base + 1] = v1[tf]; ibuf[base + 1] = i1[tf];
    }
}

// ---------- refine: one wave per token, exact f32-grid reconstruction ----------
__global__ __launch_bounds__(256) void vq_refine(
    const float* __restrict__ X, const float* __restrict__ E,
    const float* __restrict__ vbuf, const int* __restrict__ ibuf,
    const float* __restrict__ sx, const float* __restrict__ se,
    float* __restrict__ out_idx)
{
    int t = threadIdx.x;
    int n = blockIdx.x * 4 + (t >> 6);
    int lane = t & 63;

    float v = vbuf[(size_t)n * 64 + lane];
    int   ci = ibuf[(size_t)n * 64 + lane];
    float b0 = v;
#pragma unroll
    for (int m = 1; m <= 32; m <<= 1) b0 = fmaxf(b0, __shfl_xor(b0, m));

    unsigned long long mask = __ballot(v >= b0 - 1.2e-4f);

    const float* xr = X + (size_t)n * D_DIM;
    float4 xa = ((const float4*)xr)[lane * 2];
    float4 xb = ((const float4*)xr)[lane * 2 + 1];
    float sxn = sx[n];

    float bd = 1e30f; int bi = 2147483647;
    while (mask) {
        int b = (int)__builtin_ctzll(mask);
        mask &= mask - 1;
        int idx = __shfl(ci, b);
        const float* er = E + (size_t)idx * D_DIM;
        float4 ea = ((const float4*)er)[lane * 2];
        float4 eb = ((const float4*)er)[lane * 2 + 1];
        double p = (double)xa.x * ea.x + (double)xa.y * ea.y + (double)xa.z * ea.z + (double)xa.w * ea.w
                 + (double)xb.x * eb.x + (double)xb.y * eb.y + (double)xb.z * eb.z + (double)xb.w * eb.w;
#pragma unroll
        for (int m = 1; m <= 32; m <<= 1) p = p + __shfl_xor(p, m);
        float M = (float)p;
        float S = sxn + se[idx];
        float d = S - 2.0f * M;
        if (d < bd || (d == bd && idx < bi)) { bd = d; bi = idx; }
    }
    if (lane == 0) out_idx[n] = (float)bi;
}

// ---------- gather + loss ----------
__global__ __launch_bounds__(256) void vq_gather(
    const float* __restrict__ X, const float* __restrict__ E,
    const float* __restrict__ idxf, float* __restrict__ outq, float* __restrict__ outl)
{
    const int t = threadIdx.x;
    const int h = t >> 7, tt = t & 127;
    const int n = blockIdx.x * 2 + h;
    const int idx = (int)idxf[n];
    const float4* xr = (const float4*)(X + (size_t)n * D_DIM);
    const float4* er = (const float4*)(E + (size_t)idx * D_DIM);
    float4* qr = (float4*)(outq + (size_t)n * D_DIM);
    float4 x = xr[tt], e = er[tt];
    float4 dl; dl.x = e.x - x.x; dl.y = e.y - x.y; dl.z = e.z - x.z; dl.w = e.w - x.w;
    float4 qv; qv.x = x.x + dl.x; qv.y = x.y + dl.y; qv.z = x.z + dl.z; qv.w = x.w + dl.w;
    qr[tt] = qv;
    float s = dl.x * dl.x + dl.y * dl.y + dl.z * dl.z + dl.w * dl.w;
#pragma unroll
    for (int off = 32; off > 0; off >>= 1) s += __shfl_down(s, off, 64);
    __shared__ float red[4];
    if ((t & 63) == 0) red[t >> 6] = s;
    __syncthreads();
    if (tt == 0) {
        float m = (red[h * 2] + red[h * 2 + 1]) * (1.0f / (float)D_DIM);
        outl[n] = m + 0.25f * m;
    }
}

// ---------- fallback (proven round-2 path) ----------
__global__ __launch_bounds__(512) void vq_argmin_fb(
    const float* __restrict__ X, const float* __restrict__ E, float* __restrict__ out_idx)
{
    __shared__ __align__(16) unsigned char smem[48 * 1024];
    float4* Xs = (float4*)smem;
    float4* Es = (float4*)(smem + 16 * 1024);
    float*  cv = (float*)smem;
    int*    ci = (int*)(smem + 16 * 1024);
    const int t = threadIdx.x, tc = t & 31, tr = t >> 5;
    const int tok0 = blockIdx.x * 64;
    const float4* Xg = (const float4*)X;
    const float4* Eg = (const float4*)E;
    float v0[4], v1[4]; int i0[4], i1[4];
#pragma unroll
    for (int i = 0; i < 4; ++i) { v0[i] = -1e30f; v1[i] = -1e30f; i0[i] = 0; i1[i] = 1; }
    for (int kt = 0; kt < K_CODES / 128; ++kt) {
        float acc[4][4];
#pragma unroll
        for (int i = 0; i < 4; ++i)
#pragma unroll
            for (int j = 0; j < 4; ++j) acc[i][j] = 0.f;
        for (int dc = 0; dc < 8; ++dc) {
            __syncthreads();
#pragma unroll
            for (int s = 0; s < 2; ++s) {
                int id = t + s * 512; int rr = id >> 4, m = id & 15;
                Xs[rr * 16 + ((m + (rr >> 2)) & 15)] = Xg[(size_t)(tok0 + rr) * 128 + dc * 16 + m];
            }
#pragma unroll
            for (int s = 0; s < 4; ++s) {
                int id = t + s * 512; int rr = id >> 4, m = id & 15;
                Es[rr * 16 + ((m + (rr >> 2)) & 15)] = Eg[(size_t)(kt * 128 + rr) * 128 + dc * 16 + m];
            }
            __syncthreads();
#pragma unroll
            for (int dd4 = 0; dd4 < 16; ++dd4) {
                float4 xv[4], ev[4];
#pragma unroll
                for (int i = 0; i < 4; ++i) xv[i] = Xs[(4 * tr + i) * 16 + ((dd4 + tr) & 15)];
#pragma unroll
                for (int j = 0; j < 4; ++j) ev[j] = Es[(4 * tc + j) * 16 + ((dd4 + tc) & 15)];
#pragma unroll
                for (int i = 0; i < 4; ++i)
#pragma unroll
                    for (int j = 0; j < 4; ++j)
                        acc[i][j] += xv[i].x * ev[j].x + xv[i].y * ev[j].y + xv[i].z * ev[j].z + xv[i].w * ev[j].w;
            }
        }
#pragma unroll
        for (int i = 0; i < 4; ++i)
#pragma unroll
            for (int j = 0; j < 4; ++j) {
                float v = acc[i][j]; int idx = kt * 128 + 4 * tc + j;
                if (v > v0[i])      { v1[i] = v0[i]; i1[i] = i0[i]; v0[i] = v; i0[i] = idx; }
                else if (v > v1[i]) { v1[i] = v; i1[i] = idx; }
            }
    }
    __syncthreads();
#pragma unroll
    for (int i = 0; i < 4; ++i) {
        int row = 4 * tr + i;
        cv[row * 64 + 2 * tc] = v0[i];     ci[row * 64 + 2 * tc] = i0[i];
        cv[row * 64 + 2 * tc + 1] = v1[i]; ci[row * 64 + 2 * tc + 1] = i1[i];
    }
    __syncthreads();
    if (t < 64) {
        const int row = t;
        float b0 = -1e30f;
        for (int s = 0; s < 64; ++s) b0 = fmaxf(b0, cv[row * 64 + s]);
        const float* xr = X + (size_t)(tok0 + row) * D_DIM;
        const float sumx2 = np_pairwise_sq(xr);
        float bd = 1e30f; int bi = 0x7fffffff;
        for (int s = 0; s < 64; ++s) {
            float v = cv[row * 64 + s];
            if (v < b0 - 1.0e-4f) continue;
            int idx = ci[row * 64 + s];
            const float* er = E + (size_t)idx * D_DIM;
            double acc = 0.0;
            for (int d0 = 0; d0 < D_DIM; ++d0) acc += (double)xr[d0] * (double)er[d0];
            float M = (float)acc;
            float se2 = np_pairwise_sq(er);
            float S = sumx2 + se2;
            float d = S - 2.0f * M;
            if (d < bd || (d == bd && idx < bi)) { bd = d; bi = idx; }
        }
        out_idx[tok0 + row] = (float)bi;
    }
}

extern "C" void kernel_launch(void* const* d_in, const int* in_sizes, int n_in,
                              void* d_out, int out_size, void* d_ws, size_t ws_size,
                              hipStream_t stream) {
    const float* X = (const float*)d_in[0];
    const float* E = (const float*)d_in[1];
    float* out  = (float*)d_out;
    float* outq = out;
    float* outl = out + (size_t)N_TOK * D_DIM;
    float* outi = outl + N_TOK;

    const size_t WS_NEED = 33652736;  // Xim 16M + Eim 8M + vbuf 4M + ibuf 4M + sx/se
    if (ws_size >= WS_NEED) {
        unsigned char* ws = (unsigned char*)d_ws;
        unsigned char* Xim = ws;                        // 16MB
        unsigned char* Eim = ws + 16777216;             // 8MB
        float* vbuf = (float*)(ws + 25165824);          // 4MB
        int*   ibuf = (int*)(ws + 29360128);            // 4MB
        float* sx   = (float*)(ws + 33554432);          // 64KB
        float* se   = (float*)(ws + 33619968);          // 32KB
        vq_convert<<<6144, 256, 0, stream>>>(X, E, Xim, Eim);
        vq_rowsq<<<3072, 256, 0, stream>>>(X, E, sx, se);
        vq_gemm<<<512, 512, 0, stream>>>(Xim, Eim, vbuf, ibuf);
        vq_refine<<<4096, 256, 0, stream>>>(X, E, vbuf, ibuf, sx, se, outi);
    } else {
        vq_argmin_fb<<<N_TOK / 64, 512, 0, stream>>>(X, E, outi);
    }
    vq_gather<<<8192, 256, 0, stream>>>(X, E, outi, outq, outl);
}

// Round 7
// 194.527 us; speedup vs baseline: 43.0545x; 1.1283x over previous
//
#include <hip/hip_runtime.h>

// VQ-VAE vector quantizer, MI355X. N=16384 tokens, D=512, K=8192 codes, f32.
// out0: quantized_st [N*D], out1: vq_loss [N], out2: encoding_inds [N] (as float)
//
// Pass-1: rank codes by bf16 dot xh*eh via MFMA (err rms ~2.4e-6 << 1.2e-4 window).
// E streamed global->reg as fragment lines; X-hi resident in LDS (128 tokens, 128KB).
// Branchless per-element top-2 (cndmask, no divergent branches).
// Pass-2: exact f32-grid reconstruction (numpy-pairwise sums, f64->f32 dot),
// lowest-index tie-break, window 1.2e-4 on approx dot; fused gather/loss.

#define D_DIM   512
#define K_CODES 8192
#define N_TOK   16384

typedef short bf16x8 __attribute__((ext_vector_type(8)));
typedef float f32x16 __attribute__((ext_vector_type(16)));

__device__ __forceinline__ unsigned short f2bf(float x) {
    unsigned u = __float_as_uint(x);
    return (unsigned short)((u + 0x7fffu + ((u >> 16) & 1u)) >> 16);
}

// exact numpy pairwise sum of squares over 512 f32 (serial version, fallback path)
__device__ __forceinline__ float np_pairwise_sq(const float* __restrict__ a) {
    float blk[4];
#pragma unroll
    for (int b = 0; b < 4; ++b) {
        const float* p = a + b * 128;
        float r[8];
#pragma unroll
        for (int j = 0; j < 8; ++j) { double d = (double)p[j]; r[j] = (float)(d * d); }
        for (int i = 8; i < 128; i += 8) {
#pragma unroll
            for (int j = 0; j < 8; ++j) { double d = (double)p[i + j]; r[j] = r[j] + (float)(d * d); }
        }
        blk[b] = ((r[0] + r[1]) + (r[2] + r[3])) + ((r[4] + r[5]) + (r[6] + r[7]));
    }
    return (blk[0] + blk[1]) + (blk[2] + blk[3]);
}

// ---------- prep: convert (X,E -> bf16 fragment-line images) + rowsq, one launch ----------
// Ximg: [tb 128][line 128 = s*4+tf][lane 64][16B]  (128KB per tb, 16MB)
// Eimg: [cb 256][s 32][lane 64][16B]               (8MB)
// lane = hi5*32 + (row&31); data = bf16x8 of row, d = s*16 + hi5*8 ..+7
__global__ __launch_bounds__(256) void vq_prep(
    const float* __restrict__ X, const float* __restrict__ E,
    unsigned char* __restrict__ Xim, unsigned char* __restrict__ Eim,
    float* __restrict__ sx, float* __restrict__ se)
{
    const int bid = blockIdx.x;
    const int t = threadIdx.x;
    if (bid < 4096) {            // X convert
        int tid = bid * 256 + t;
        int tb = tid >> 13, rem = tid & 8191;
        int line = rem >> 6, lane = rem & 63;
        int s = line >> 2, tf = line & 3;
        int token = tb * 128 + tf * 32 + (lane & 31);
        int d0 = s * 16 + (lane >> 5) * 8;
        const float* p = X + (size_t)token * D_DIM + d0;
        unsigned h[8];
#pragma unroll
        for (int j = 0; j < 8; ++j) h[j] = f2bf(p[j]);
        uint4 hv = make_uint4(h[0]|(h[1]<<16), h[2]|(h[3]<<16), h[4]|(h[5]<<16), h[6]|(h[7]<<16));
        *(uint4*)(Xim + (size_t)tb * 131072 + (size_t)line * 1024 + (size_t)lane * 16) = hv;
    } else if (bid < 6144) {     // E convert
        int id2 = (bid - 4096) * 256 + t;
        int cb = id2 >> 11, rem = id2 & 2047;
        int s = rem >> 6, lane = rem & 63;
        int code = cb * 32 + (lane & 31);
        int d0 = s * 16 + (lane >> 5) * 8;
        const float* p = E + (size_t)code * D_DIM + d0;
        unsigned h[8];
#pragma unroll
        for (int j = 0; j < 8; ++j) h[j] = f2bf(p[j]);
        uint4 hv = make_uint4(h[0]|(h[1]<<16), h[2]|(h[3]<<16), h[4]|(h[5]<<16), h[6]|(h[7]<<16));
        *(uint4*)(Eim + (size_t)cb * 32768 + (size_t)s * 1024 + (size_t)lane * 16) = hv;
    } else {                     // rowsq (exact numpy-pairwise, 32 lanes per row)
        int wv = (bid - 6144) * 4 + (t >> 6);
        int sub = (t >> 5) & 1, l32 = t & 31;
        int row = wv * 2 + sub;
        const float* p;
        float* dst;
        if (row < N_TOK) { p = X + (size_t)row * D_DIM; dst = sx + row; }
        else if (row < N_TOK + K_CODES) { p = E + (size_t)(row - N_TOK) * D_DIM; dst = se + (row - N_TOK); }
        else return;
        int b = l32 >> 3, rr = l32 & 7;
        const float* q = p + b * 128 + rr;
        double d0 = (double)q[0];
        float r = (float)(d0 * d0);
#pragma unroll
        for (int i = 1; i < 16; ++i) { double d = (double)q[8 * i]; r = r + (float)(d * d); }
#pragma unroll
        for (int m = 1; m <= 16; m <<= 1) r = r + __shfl_xor(r, m);
        if (l32 == 0) *dst = r;
    }
}

// branchless top-2 insert (strict > keeps lowest index on exact ties; ascending visit order)
#define INS(vv, cc, T) { \
    float _v = (vv); int _c = (cc); \
    bool _g0 = _v > v0[T]; \
    bool _g1 = _v > v1[T]; \
    float _m = _g1 ? _v : v1[T]; \
    int   _mi = _g1 ? _c : i1[T]; \
    v1[T] = _g0 ? v0[T] : _m; \
    i1[T] = _g0 ? i0[T] : _mi; \
    v0[T] = _g0 ? _v : v0[T]; \
    i0[T] = _g0 ? _c : i0[T]; \
}

#define MFMA(A, B, C) C = __builtin_amdgcn_mfma_f32_32x32x16_bf16(A, B, C, 0, 0, 0)

// ---------- pass-1 GEMM: block = 512 codes x 128 tokens slice of the q-half ----------
// Grid 256 = 128 tb x 2 q, XCD-pinned so each XCD's E working set is its 4MB q-half.
__global__ __launch_bounds__(512, 2) void vq_gemm(
    const unsigned char* __restrict__ Xim, const unsigned char* __restrict__ Eim,
    float* __restrict__ vbuf, int* __restrict__ ibuf)
{
    __shared__ unsigned int smemU[32768];  // 128 KiB: X-hi fragment lines
    const int tid = threadIdx.x;
    const int lane = tid & 63, w = tid >> 6;
    const int hi5 = lane >> 5, l31 = lane & 31;

    const int bid  = blockIdx.x;
    const int xcd  = bid & 7, slot = bid >> 3;   // slot 0..31
    const int q    = xcd >> 2;
    const int tb   = (xcd & 3) * 32 + slot;

    // stage X block image (128 KiB) linearly into LDS
    {
        const unsigned char* src = Xim + (size_t)tb * 131072;
#pragma unroll
        for (int c = 0; c < 16; ++c) {
            int off  = (c * 512 + tid) * 16;
            int doff = (c * 512 + w * 64) * 16;   // wave-uniform dest base
            __builtin_amdgcn_global_load_lds((const unsigned int*)(src + off),
                                             (unsigned int*)((unsigned char*)smemU + doff), 16, 0, 0);
        }
    }
    __syncthreads();

    const unsigned char* smemB = (const unsigned char*)smemU;
    const int laneB = lane * 16;

    float v0[4], v1[4]; int i0[4], i1[4];
#pragma unroll
    for (int tf = 0; tf < 4; ++tf) { v0[tf] = -1e30f; v1[tf] = -1e30f; i0[tf] = 0; i1[tf] = 1; }

#pragma unroll 1
    for (int ck = 0; ck < 8; ++ck) {
        const int cb0 = q * 128 + ck * 16 + w * 2;           // 32-code block units
        const unsigned char* Ap0 = Eim + (size_t)cb0 * 32768;
        const unsigned char* Ap1 = Ap0 + 32768;

        f32x16 a00 = {}, a01 = {}, a02 = {}, a03 = {};
        f32x16 a10 = {}, a11 = {}, a12 = {}, a13 = {};

        bf16x8 A0a = *(const bf16x8*)(Ap0 + laneB);
        bf16x8 A1a = *(const bf16x8*)(Ap1 + laneB);
        bf16x8 B0a = *(const bf16x8*)(smemB + 0 * 1024 + laneB);
        bf16x8 B1a = *(const bf16x8*)(smemB + 1 * 1024 + laneB);
        bf16x8 B2a = *(const bf16x8*)(smemB + 2 * 1024 + laneB);
        bf16x8 B3a = *(const bf16x8*)(smemB + 3 * 1024 + laneB);

#pragma unroll 1
        for (int s2 = 0; s2 < 16; ++s2) {
            const int so_ = 2 * s2 + 1, sn_ = (2 * s2 + 2) & 31;

            // prefetch odd-step A (global) and B (LDS)
            bf16x8 A0b = *(const bf16x8*)(Ap0 + (size_t)so_ * 1024 + laneB);
            bf16x8 A1b = *(const bf16x8*)(Ap1 + (size_t)so_ * 1024 + laneB);
            bf16x8 B0b = *(const bf16x8*)(smemB + (so_ * 4 + 0) * 1024 + laneB);
            bf16x8 B1b = *(const bf16x8*)(smemB + (so_ * 4 + 1) * 1024 + laneB);
            bf16x8 B2b = *(const bf16x8*)(smemB + (so_ * 4 + 2) * 1024 + laneB);
            bf16x8 B3b = *(const bf16x8*)(smemB + (so_ * 4 + 3) * 1024 + laneB);

            // even step: dependency distance 8
            MFMA(A0a, B0a, a00); MFMA(A1a, B0a, a10);
            MFMA(A0a, B1a, a01); MFMA(A1a, B1a, a11);
            MFMA(A0a, B2a, a02); MFMA(A1a, B2a, a12);
            MFMA(A0a, B3a, a03); MFMA(A1a, B3a, a13);

            // prefetch next even step (wraps on last iter; value unused, in-bounds)
            A0a = *(const bf16x8*)(Ap0 + (size_t)sn_ * 1024 + laneB);
            A1a = *(const bf16x8*)(Ap1 + (size_t)sn_ * 1024 + laneB);
            B0a = *(const bf16x8*)(smemB + (sn_ * 4 + 0) * 1024 + laneB);
            B1a = *(const bf16x8*)(smemB + (sn_ * 4 + 1) * 1024 + laneB);
            B2a = *(const bf16x8*)(smemB + (sn_ * 4 + 2) * 1024 + laneB);
            B3a = *(const bf16x8*)(smemB + (sn_ * 4 + 3) * 1024 + laneB);

            // odd step
            MFMA(A0b, B0b, a00); MFMA(A1b, B0b, a10);
            MFMA(A0b, B1b, a01); MFMA(A1b, B1b, a11);
            MFMA(A0b, B2b, a02); MFMA(A1b, B2b, a12);
            MFMA(A0b, B3b, a03); MFMA(A1b, B3b, a13);
        }

        // branchless top-2 insert, ascending code order within each acc
        const int cbase0 = cb0 * 32 + 4 * hi5;
        const int cbase1 = cbase0 + 32;
#pragma unroll
        for (int g = 0; g < 16; ++g) {
            const int pat = (g & 3) + 8 * (g >> 2);
            int cA = cbase0 + pat, cB = cbase1 + pat;
            INS(a00[g], cA, 0); INS(a01[g], cA, 1); INS(a02[g], cA, 2); INS(a03[g], cA, 3);
            INS(a10[g], cB, 0); INS(a11[g], cB, 1); INS(a12[g], cB, 2); INS(a13[g], cB, 3);
        }
    }

#pragma unroll
    for (int tf = 0; tf < 4; ++tf) {
        int token = tb * 128 + tf * 32 + l31;
        int slot2 = q * 32 + w * 4 + hi5 * 2;
        size_t base = (size_t)token * 64 + slot2;
        vbuf[base] = v0[tf];     ibuf[base] = i0[tf];
        vbuf[base + 1] = v1[tf]; ibuf[base + 1] = i1[tf];
    }
}

// ---------- refine + gather fused: one wave per token ----------
__global__ __launch_bounds__(256) void vq_refine(
    const float* __restrict__ X, const float* __restrict__ E,
    const float* __restrict__ vbuf, const int* __restrict__ ibuf,
    const float* __restrict__ sx, const float* __restrict__ se,
    float* __restrict__ out_idx, float* __restrict__ outq, float* __restrict__ outl)
{
    int t = threadIdx.x;
    int n = blockIdx.x * 4 + (t >> 6);
    int lane = t & 63;

    float v = vbuf[(size_t)n * 64 + lane];
    int   ci = ibuf[(size_t)n * 64 + lane];
    float b0 = v;
#pragma unroll
    for (int m = 1; m <= 32; m <<= 1) b0 = fmaxf(b0, __shfl_xor(b0, m));

    unsigned long long mask = __ballot(v >= b0 - 1.2e-4f);

    const float* xr = X + (size_t)n * D_DIM;
    float4 xa = ((const float4*)xr)[lane * 2];
    float4 xb = ((const float4*)xr)[lane * 2 + 1];
    float sxn = sx[n];

    float bd = 1e30f; int bi = 2147483647;
    while (mask) {
        int b = (int)__builtin_ctzll(mask);
        mask &= mask - 1;
        int idx = __shfl(ci, b);
        const float* er = E + (size_t)idx * D_DIM;
        float4 ea = ((const float4*)er)[lane * 2];
        float4 eb = ((const float4*)er)[lane * 2 + 1];
        double p = (double)xa.x * ea.x + (double)xa.y * ea.y + (double)xa.z * ea.z + (double)xa.w * ea.w
                 + (double)xb.x * eb.x + (double)xb.y * eb.y + (double)xb.z * eb.z + (double)xb.w * eb.w;
#pragma unroll
        for (int m = 1; m <= 32; m <<= 1) p = p + __shfl_xor(p, m);
        float M = (float)p;
        float S = sxn + se[idx];
        float d = S - 2.0f * M;
        if (d < bd || (d == bd && idx < bi)) { bd = d; bi = idx; }
    }
    if (lane == 0) out_idx[n] = (float)bi;

    // fused gather + loss
    const float* er = E + (size_t)bi * D_DIM;
    float4 ea = ((const float4*)er)[lane * 2];
    float4 eb = ((const float4*)er)[lane * 2 + 1];
    float4 da, db;
    da.x = ea.x - xa.x; da.y = ea.y - xa.y; da.z = ea.z - xa.z; da.w = ea.w - xa.w;
    db.x = eb.x - xb.x; db.y = eb.y - xb.y; db.z = eb.z - xb.z; db.w = eb.w - xb.w;
    float4 qa, qb;
    qa.x = xa.x + da.x; qa.y = xa.y + da.y; qa.z = xa.z + da.z; qa.w = xa.w + da.w;
    qb.x = xb.x + db.x; qb.y = xb.y + db.y; qb.z = xb.z + db.z; qb.w = xb.w + db.w;
    float4* qr = (float4*)(outq + (size_t)n * D_DIM);
    qr[lane * 2] = qa;
    qr[lane * 2 + 1] = qb;
    float s = da.x * da.x + da.y * da.y + da.z * da.z + da.w * da.w
            + db.x * db.x + db.y * db.y + db.z * db.z + db.w * db.w;
#pragma unroll
    for (int m = 1; m <= 32; m <<= 1) s += __shfl_xor(s, m);
    if (lane == 0) {
        float mmean = s * (1.0f / (float)D_DIM);
        outl[n] = mmean + 0.25f * mmean;
    }
}

// ---------- fallback path (proven round-2 kernels, used only if ws too small) ----------
__global__ __launch_bounds__(512) void vq_argmin_fb(
    const float* __restrict__ X, const float* __restrict__ E, float* __restrict__ out_idx)
{
    __shared__ __align__(16) unsigned char smem[48 * 1024];
    float4* Xs = (float4*)smem;
    float4* Es = (float4*)(smem + 16 * 1024);
    float*  cv = (float*)smem;
    int*    ci = (int*)(smem + 16 * 1024);
    const int t = threadIdx.x, tc = t & 31, tr = t >> 5;
    const int tok0 = blockIdx.x * 64;
    const float4* Xg = (const float4*)X;
    const float4* Eg = (const float4*)E;
    float v0[4], v1[4]; int i0[4], i1[4];
#pragma unroll
    for (int i = 0; i < 4; ++i) { v0[i] = -1e30f; v1[i] = -1e30f; i0[i] = 0; i1[i] = 1; }
    for (int kt = 0; kt < K_CODES / 128; ++kt) {
        float acc[4][4];
#pragma unroll
        for (int i = 0; i < 4; ++i)
#pragma unroll
            for (int j = 0; j < 4; ++j) acc[i][j] = 0.f;
        for (int dc = 0; dc < 8; ++dc) {
            __syncthreads();
#pragma unroll
            for (int s = 0; s < 2; ++s) {
                int id = t + s * 512; int rr = id >> 4, m = id & 15;
                Xs[rr * 16 + ((m + (rr >> 2)) & 15)] = Xg[(size_t)(tok0 + rr) * 128 + dc * 16 + m];
            }
#pragma unroll
            for (int s = 0; s < 4; ++s) {
                int id = t + s * 512; int rr = id >> 4, m = id & 15;
                Es[rr * 16 + ((m + (rr >> 2)) & 15)] = Eg[(size_t)(kt * 128 + rr) * 128 + dc * 16 + m];
            }
            __syncthreads();
#pragma unroll
            for (int dd4 = 0; dd4 < 16; ++dd4) {
                float4 xv[4], ev[4];
#pragma unroll
                for (int i = 0; i < 4; ++i) xv[i] = Xs[(4 * tr + i) * 16 + ((dd4 + tr) & 15)];
#pragma unroll
                for (int j = 0; j < 4; ++j) ev[j] = Es[(4 * tc + j) * 16 + ((dd4 + tc) & 15)];
#pragma unroll
                for (int i = 0; i < 4; ++i)
#pragma unroll
                    for (int j = 0; j < 4; ++j)
                        acc[i][j] += xv[i].x * ev[j].x + xv[i].y * ev[j].y + xv[i].z * ev[j].z + xv[i].w * ev[j].w;
            }
        }
#pragma unroll
        for (int i = 0; i < 4; ++i)
#pragma unroll
            for (int j = 0; j < 4; ++j) {
                float v = acc[i][j]; int idx = kt * 128 + 4 * tc + j;
                if (v > v0[i])      { v1[i] = v0[i]; i1[i] = i0[i]; v0[i] = v; i0[i] = idx; }
                else if (v > v1[i]) { v1[i] = v; i1[i] = idx; }
            }
    }
    __syncthreads();
#pragma unroll
    for (int i = 0; i < 4; ++i) {
        int row = 4 * tr + i;
        cv[row * 64 + 2 * tc] = v0[i];     ci[row * 64 + 2 * tc] = i0[i];
        cv[row * 64 + 2 * tc + 1] = v1[i]; ci[row * 64 + 2 * tc + 1] = i1[i];
    }
    __syncthreads();
    if (t < 64) {
        const int row = t;
        float b0 = -1e30f;
        for (int s = 0; s < 64; ++s) b0 = fmaxf(b0, cv[row * 64 + s]);
        const float* xr = X + (size_t)(tok0 + row) * D_DIM;
        const float sumx2 = np_pairwise_sq(xr);
        float bd = 1e30f; int bi = 0x7fffffff;
        for (int s = 0; s < 64; ++s) {
            float v = cv[row * 64 + s];
            if (v < b0 - 1.0e-4f) continue;
            int idx = ci[row * 64 + s];
            const float* er = E + (size_t)idx * D_DIM;
            double acc = 0.0;
            for (int d0 = 0; d0 < D_DIM; ++d0) acc += (double)xr[d0] * (double)er[d0];
            float M = (float)acc;
            float se2 = np_pairwise_sq(er);
            float S = sumx2 + se2;
            float d = S - 2.0f * M;
            if (d < bd || (d == bd && idx < bi)) { bd = d; bi = idx; }
        }
        out_idx[tok0 + row] = (float)bi;
    }
}

__global__ __launch_bounds__(256) void vq_gather_fb(
    const float* __restrict__ X, const float* __restrict__ E,
    const float* __restrict__ idxf, float* __restrict__ outq, float* __restrict__ outl)
{
    const int t = threadIdx.x;
    const int h = t >> 7, tt = t & 127;
    const int n = blockIdx.x * 2 + h;
    const int idx = (int)idxf[n];
    const float4* xr = (const float4*)(X + (size_t)n * D_DIM);
    const float4* er = (const float4*)(E + (size_t)idx * D_DIM);
    float4* qr = (float4*)(outq + (size_t)n * D_DIM);
    float4 x = xr[tt], e = er[tt];
    float4 dl; dl.x = e.x - x.x; dl.y = e.y - x.y; dl.z = e.z - x.z; dl.w = e.w - x.w;
    float4 qv; qv.x = x.x + dl.x; qv.y = x.y + dl.y; qv.z = x.z + dl.z; qv.w = x.w + dl.w;
    qr[tt] = qv;
    float s = dl.x * dl.x + dl.y * dl.y + dl.z * dl.z + dl.w * dl.w;
#pragma unroll
    for (int off = 32; off > 0; off >>= 1) s += __shfl_down(s, off, 64);
    __shared__ float red[4];
    if ((t & 63) == 0) red[t >> 6] = s;
    __syncthreads();
    if (tt == 0) {
        float m = (red[h * 2] + red[h * 2 + 1]) * (1.0f / (float)D_DIM);
        outl[n] = m + 0.25f * m;
    }
}

extern "C" void kernel_launch(void* const* d_in, const int* in_sizes, int n_in,
                              void* d_out, int out_size, void* d_ws, size_t ws_size,
                              hipStream_t stream) {
    const float* X = (const float*)d_in[0];
    const float* E = (const float*)d_in[1];
    float* out  = (float*)d_out;
    float* outq = out;
    float* outl = out + (size_t)N_TOK * D_DIM;
    float* outi = outl + N_TOK;

    const size_t WS_NEED = 33652736;  // Xim 16M + Eim 8M + vbuf 4M + ibuf 4M + sx/se
    if (ws_size >= WS_NEED) {
        unsigned char* ws = (unsigned char*)d_ws;
        unsigned char* Xim = ws;                        // 16MB
        unsigned char* Eim = ws + 16777216;             // 8MB
        float* vbuf = (float*)(ws + 25165824);          // 4MB
        int*   ibuf = (int*)(ws + 29360128);            // 4MB
        float* sx   = (float*)(ws + 33554432);          // 64KB
        float* se   = (float*)(ws + 33619968);          // 32KB
        vq_prep<<<9216, 256, 0, stream>>>(X, E, Xim, Eim, sx, se);
        vq_gemm<<<256, 512, 0, stream>>>(Xim, Eim, vbuf, ibuf);
        vq_refine<<<4096, 256, 0, stream>>>(X, E, vbuf, ibuf, sx, se, outi, outq, outl);
    } else {
        vq_argmin_fb<<<N_TOK / 64, 512, 0, stream>>>(X, E, outi);
        vq_gather_fb<<<8192, 256, 0, stream>>>(X, E, outi, outq, outl);
    }
}

// Round 8
// 178.918 us; speedup vs baseline: 46.8105x; 1.0872x over previous
//
#include <hip/hip_runtime.h>

// VQ-VAE vector quantizer, MI355X. N=16384 tokens, D=512, K=8192 codes, f32.
// out0: quantized_st [N*D], out1: vq_loss [N], out2: encoding_inds [N] (as float)
//
// Pass-1: rank codes by bf16 dot xh*eh via MFMA (err rms ~2.4e-6 << 1.2e-4 window).
// MFMA accumulator initialized to 4.625f -> final acc in [4.5,4.75) (|dot| <= 0.072
// hard bound), so f32 bits are u32-monotone within the block; key = (bits<<13) +
// (8191-code) gives branchless 3-op streaming top-2 (min/max), index embedded.
// Pass-2: exact f32-grid reconstruction (numpy-pairwise sums, f64->f32 dot),
// lowest-index tie-break, window 1.2e-4 on approx dot; fused gather/loss.

#define D_DIM   512
#define K_CODES 8192
#define N_TOK   16384

typedef short bf16x8 __attribute__((ext_vector_type(8)));
typedef float f32x16 __attribute__((ext_vector_type(16)));

__device__ __forceinline__ unsigned short f2bf(float x) {
    unsigned u = __float_as_uint(x);
    return (unsigned short)((u + 0x7fffu + ((u >> 16) & 1u)) >> 16);
}

// exact numpy pairwise sum of squares over 512 f32 (serial version, fallback path)
__device__ __forceinline__ float np_pairwise_sq(const float* __restrict__ a) {
    float blk[4];
#pragma unroll
    for (int b = 0; b < 4; ++b) {
        const float* p = a + b * 128;
        float r[8];
#pragma unroll
        for (int j = 0; j < 8; ++j) { double d = (double)p[j]; r[j] = (float)(d * d); }
        for (int i = 8; i < 128; i += 8) {
#pragma unroll
            for (int j = 0; j < 8; ++j) { double d = (double)p[i + j]; r[j] = r[j] + (float)(d * d); }
        }
        blk[b] = ((r[0] + r[1]) + (r[2] + r[3])) + ((r[4] + r[5]) + (r[6] + r[7]));
    }
    return (blk[0] + blk[1]) + (blk[2] + blk[3]);
}

// ---------- prep: convert (X,E -> bf16 fragment-line images) + rowsq, one launch ----------
// Ximg: [tb 128][line 128 = s*4+tf][lane 64][16B]  (128KB per tb, 16MB)
// Eimg: [cb 256][s 32][lane 64][16B]               (8MB)
__global__ __launch_bounds__(256) void vq_prep(
    const float* __restrict__ X, const float* __restrict__ E,
    unsigned char* __restrict__ Xim, unsigned char* __restrict__ Eim,
    float* __restrict__ sx, float* __restrict__ se)
{
    const int bid = blockIdx.x;
    const int t = threadIdx.x;
    if (bid < 4096) {            // X convert
        int tid = bid * 256 + t;
        int tb = tid >> 13, rem = tid & 8191;
        int line = rem >> 6, lane = rem & 63;
        int s = line >> 2, tf = line & 3;
        int token = tb * 128 + tf * 32 + (lane & 31);
        int d0 = s * 16 + (lane >> 5) * 8;
        const float* p = X + (size_t)token * D_DIM + d0;
        unsigned h[8];
#pragma unroll
        for (int j = 0; j < 8; ++j) h[j] = f2bf(p[j]);
        uint4 hv = make_uint4(h[0]|(h[1]<<16), h[2]|(h[3]<<16), h[4]|(h[5]<<16), h[6]|(h[7]<<16));
        *(uint4*)(Xim + (size_t)tb * 131072 + (size_t)line * 1024 + (size_t)lane * 16) = hv;
    } else if (bid < 6144) {     // E convert
        int id2 = (bid - 4096) * 256 + t;
        int cb = id2 >> 11, rem = id2 & 2047;
        int s = rem >> 6, lane = rem & 63;
        int code = cb * 32 + (lane & 31);
        int d0 = s * 16 + (lane >> 5) * 8;
        const float* p = E + (size_t)code * D_DIM + d0;
        unsigned h[8];
#pragma unroll
        for (int j = 0; j < 8; ++j) h[j] = f2bf(p[j]);
        uint4 hv = make_uint4(h[0]|(h[1]<<16), h[2]|(h[3]<<16), h[4]|(h[5]<<16), h[6]|(h[7]<<16));
        *(uint4*)(Eim + (size_t)cb * 32768 + (size_t)s * 1024 + (size_t)lane * 16) = hv;
    } else {                     // rowsq (exact numpy-pairwise, 32 lanes per row)
        int wv = (bid - 6144) * 4 + (t >> 6);
        int sub = (t >> 5) & 1, l32 = t & 31;
        int row = wv * 2 + sub;
        const float* p;
        float* dst;
        if (row < N_TOK) { p = X + (size_t)row * D_DIM; dst = sx + row; }
        else if (row < N_TOK + K_CODES) { p = E + (size_t)(row - N_TOK) * D_DIM; dst = se + (row - N_TOK); }
        else return;
        int b = l32 >> 3, rr = l32 & 7;
        const float* q = p + b * 128 + rr;
        double d0 = (double)q[0];
        float r = (float)(d0 * d0);
#pragma unroll
        for (int i = 1; i < 16; ++i) { double d = (double)q[8 * i]; r = r + (float)(d * d); }
#pragma unroll
        for (int m = 1; m <= 16; m <<= 1) r = r + __shfl_xor(r, m);
        if (l32 == 0) *dst = r;
    }
}

#define MFMA(A, B, C) C = __builtin_amdgcn_mfma_f32_32x32x16_bf16(A, B, C, 0, 0, 0)

// streaming top-2 on sortable u32 keys: 3 VALU (v_min_u32 + 2 v_max_u32)
#define UPD(T, P) { unsigned _p = (P); \
    unsigned _mn = _p < m0[T] ? _p : m0[T]; \
    m1[T] = _mn > m1[T] ? _mn : m1[T]; \
    m0[T] = _p > m0[T] ? _p : m0[T]; }

// ---------- pass-1 GEMM: block = 512 codes x 128 tokens slice of the q-half ----------
// Grid 256 = 128 tb x 2 q, XCD-pinned so each XCD's E working set is its 4MB q-half.
__global__ __launch_bounds__(512, 2) void vq_gemm(
    const unsigned char* __restrict__ Xim, const unsigned char* __restrict__ Eim,
    float* __restrict__ vbuf, int* __restrict__ ibuf)
{
    __shared__ unsigned int smemU[32768];  // 128 KiB: X-hi fragment lines
    const int tid = threadIdx.x;
    const int lane = tid & 63, w = tid >> 6;
    const int hi5 = lane >> 5, l31 = lane & 31;

    const int bid  = blockIdx.x;
    const int xcd  = bid & 7, slot = bid >> 3;   // slot 0..31
    const int q    = xcd >> 2;
    const int tb   = (xcd & 3) * 32 + slot;

    // stage X block image (128 KiB) linearly into LDS
    {
        const unsigned char* src = Xim + (size_t)tb * 131072;
#pragma unroll
        for (int c = 0; c < 16; ++c) {
            int off  = (c * 512 + tid) * 16;
            int doff = (c * 512 + w * 64) * 16;   // wave-uniform dest base
            __builtin_amdgcn_global_load_lds((const unsigned int*)(src + off),
                                             (unsigned int*)((unsigned char*)smemU + doff), 16, 0, 0);
        }
    }
    __syncthreads();

    const unsigned char* smemB = (const unsigned char*)smemU;
    const int laneB = lane * 16;

    f32x16 AINIT;
#pragma unroll
    for (int i = 0; i < 16; ++i) AINIT[i] = 4.625f;   // bias: final acc in [4.5, 4.75)

    unsigned m0[4], m1[4];   // packed top-2 keys per token-frag
#pragma unroll
    for (int tf = 0; tf < 4; ++tf) { m0[tf] = 0u; m1[tf] = 0u; }

#pragma unroll 1
    for (int ck = 0; ck < 8; ++ck) {
        const int cb0 = q * 128 + ck * 16 + w * 2;           // 32-code block units
        const unsigned char* Ap0 = Eim + (size_t)cb0 * 32768;
        const unsigned char* Ap1 = Ap0 + 32768;

        f32x16 a00 = AINIT, a01 = AINIT, a02 = AINIT, a03 = AINIT;
        f32x16 a10 = AINIT, a11 = AINIT, a12 = AINIT, a13 = AINIT;

        bf16x8 A0a = *(const bf16x8*)(Ap0 + laneB);
        bf16x8 A1a = *(const bf16x8*)(Ap1 + laneB);
        bf16x8 B0a = *(const bf16x8*)(smemB + 0 * 1024 + laneB);
        bf16x8 B1a = *(const bf16x8*)(smemB + 1 * 1024 + laneB);
        bf16x8 B2a = *(const bf16x8*)(smemB + 2 * 1024 + laneB);
        bf16x8 B3a = *(const bf16x8*)(smemB + 3 * 1024 + laneB);

#pragma unroll 1
        for (int s2 = 0; s2 < 16; ++s2) {
            const int so_ = 2 * s2 + 1, sn_ = (2 * s2 + 2) & 31;

            // prefetch odd-step A (global) and B (LDS)
            bf16x8 A0b = *(const bf16x8*)(Ap0 + (size_t)so_ * 1024 + laneB);
            bf16x8 A1b = *(const bf16x8*)(Ap1 + (size_t)so_ * 1024 + laneB);
            bf16x8 B0b = *(const bf16x8*)(smemB + (so_ * 4 + 0) * 1024 + laneB);
            bf16x8 B1b = *(const bf16x8*)(smemB + (so_ * 4 + 1) * 1024 + laneB);
            bf16x8 B2b = *(const bf16x8*)(smemB + (so_ * 4 + 2) * 1024 + laneB);
            bf16x8 B3b = *(const bf16x8*)(smemB + (so_ * 4 + 3) * 1024 + laneB);

            // even step: dependency distance 8
            MFMA(A0a, B0a, a00); MFMA(A1a, B0a, a10);
            MFMA(A0a, B1a, a01); MFMA(A1a, B1a, a11);
            MFMA(A0a, B2a, a02); MFMA(A1a, B2a, a12);
            MFMA(A0a, B3a, a03); MFMA(A1a, B3a, a13);

            // prefetch next even step (wraps on last iter; value unused, in-bounds)
            A0a = *(const bf16x8*)(Ap0 + (size_t)sn_ * 1024 + laneB);
            A1a = *(const bf16x8*)(Ap1 + (size_t)sn_ * 1024 + laneB);
            B0a = *(const bf16x8*)(smemB + (sn_ * 4 + 0) * 1024 + laneB);
            B1a = *(const bf16x8*)(smemB + (sn_ * 4 + 1) * 1024 + laneB);
            B2a = *(const bf16x8*)(smemB + (sn_ * 4 + 2) * 1024 + laneB);
            B3a = *(const bf16x8*)(smemB + (sn_ * 4 + 3) * 1024 + laneB);

            // odd step
            MFMA(A0b, B0b, a00); MFMA(A1b, B0b, a10);
            MFMA(A0b, B1b, a01); MFMA(A1b, B1b, a11);
            MFMA(A0b, B2b, a02); MFMA(A1b, B2b, a12);
            MFMA(A0b, B3b, a03); MFMA(A1b, B3b, a13);
        }

        // key-packed top-2 update. code = cbase + pat; key low 13 bits = 8191-code.
        const int cbase0 = cb0 * 32 + 4 * hi5;
        const unsigned binv0 = 8191u - (unsigned)cbase0;         // accf 0
        const unsigned binv1 = binv0 - 32u;                      // accf 1
#pragma unroll
        for (int g = 0; g < 16; ++g) {
            const unsigned pat = (unsigned)((g & 3) + 8 * (g >> 2));
            const unsigned bp0 = binv0 - pat;
            const unsigned bp1 = binv1 - pat;
            UPD(0, (__float_as_uint(a00[g]) << 13) + bp0);
            UPD(1, (__float_as_uint(a01[g]) << 13) + bp0);
            UPD(2, (__float_as_uint(a02[g]) << 13) + bp0);
            UPD(3, (__float_as_uint(a03[g]) << 13) + bp0);
            UPD(0, (__float_as_uint(a10[g]) << 13) + bp1);
            UPD(1, (__float_as_uint(a11[g]) << 13) + bp1);
            UPD(2, (__float_as_uint(a12[g]) << 13) + bp1);
            UPD(3, (__float_as_uint(a13[g]) << 13) + bp1);
        }
    }

#pragma unroll
    for (int tf = 0; tf < 4; ++tf) {
        int token = tb * 128 + tf * 32 + l31;
        int slot2 = q * 32 + w * 4 + hi5 * 2;
        size_t base = (size_t)token * 64 + slot2;
        // unpack: bits[31:19] of all acc values are those of 4.5f (0x40900000)
        float v0f = __uint_as_float((m0[tf] >> 13) | 0x40900000u) - 4.625f;
        float v1f = __uint_as_float((m1[tf] >> 13) | 0x40900000u) - 4.625f;
        int   i0v = 8191 - (int)(m0[tf] & 8191u);
        int   i1v = 8191 - (int)(m1[tf] & 8191u);
        vbuf[base] = v0f;     ibuf[base] = i0v;
        vbuf[base + 1] = v1f; ibuf[base + 1] = i1v;
    }
}

// ---------- refine + gather fused: one wave per token ----------
__global__ __launch_bounds__(256) void vq_refine(
    const float* __restrict__ X, const float* __restrict__ E,
    const float* __restrict__ vbuf, const int* __restrict__ ibuf,
    const float* __restrict__ sx, const float* __restrict__ se,
    float* __restrict__ out_idx, float* __restrict__ outq, float* __restrict__ outl)
{
    int t = threadIdx.x;
    int n = blockIdx.x * 4 + (t >> 6);
    int lane = t & 63;

    float v = vbuf[(size_t)n * 64 + lane];
    int   ci = ibuf[(size_t)n * 64 + lane];
    float b0 = v;
#pragma unroll
    for (int m = 1; m <= 32; m <<= 1) b0 = fmaxf(b0, __shfl_xor(b0, m));

    unsigned long long mask = __ballot(v >= b0 - 1.2e-4f);

    const float* xr = X + (size_t)n * D_DIM;
    float4 xa = ((const float4*)xr)[lane * 2];
    float4 xb = ((const float4*)xr)[lane * 2 + 1];
    float sxn = sx[n];

    float bd = 1e30f; int bi = 2147483647;
    while (mask) {
        int b = (int)__builtin_ctzll(mask);
        mask &= mask - 1;
        int idx = __shfl(ci, b);
        const float* er = E + (size_t)idx * D_DIM;
        float4 ea = ((const float4*)er)[lane * 2];
        float4 eb = ((const float4*)er)[lane * 2 + 1];
        double p = (double)xa.x * ea.x + (double)xa.y * ea.y + (double)xa.z * ea.z + (double)xa.w * ea.w
                 + (double)xb.x * eb.x + (double)xb.y * eb.y + (double)xb.z * eb.z + (double)xb.w * eb.w;
#pragma unroll
        for (int m = 1; m <= 32; m <<= 1) p = p + __shfl_xor(p, m);
        float M = (float)p;
        float S = sxn + se[idx];
        float d = S - 2.0f * M;
        if (d < bd || (d == bd && idx < bi)) { bd = d; bi = idx; }
    }
    if (lane == 0) out_idx[n] = (float)bi;

    // fused gather + loss
    const float* er = E + (size_t)bi * D_DIM;
    float4 ea = ((const float4*)er)[lane * 2];
    float4 eb = ((const float4*)er)[lane * 2 + 1];
    float4 da, db;
    da.x = ea.x - xa.x; da.y = ea.y - xa.y; da.z = ea.z - xa.z; da.w = ea.w - xa.w;
    db.x = eb.x - xb.x; db.y = eb.y - xb.y; db.z = eb.z - xb.z; db.w = eb.w - xb.w;
    float4 qa, qb;
    qa.x = xa.x + da.x; qa.y = xa.y + da.y; qa.z = xa.z + da.z; qa.w = xa.w + da.w;
    qb.x = xb.x + db.x; qb.y = xb.y + db.y; qb.z = xb.z + db.z; qb.w = xb.w + db.w;
    float4* qr = (float4*)(outq + (size_t)n * D_DIM);
    qr[lane * 2] = qa;
    qr[lane * 2 + 1] = qb;
    float s = da.x * da.x + da.y * da.y + da.z * da.z + da.w * da.w
            + db.x * db.x + db.y * db.y + db.z * db.z + db.w * db.w;
#pragma unroll
    for (int m = 1; m <= 32; m <<= 1) s += __shfl_xor(s, m);
    if (lane == 0) {
        float mmean = s * (1.0f / (float)D_DIM);
        outl[n] = mmean + 0.25f * mmean;
    }
}

// ---------- fallback path (proven round-2 kernels, used only if ws too small) ----------
__global__ __launch_bounds__(512) void vq_argmin_fb(
    const float* __restrict__ X, const float* __restrict__ E, float* __restrict__ out_idx)
{
    __shared__ __align__(16) unsigned char smem[48 * 1024];
    float4* Xs = (float4*)smem;
    float4* Es = (float4*)(smem + 16 * 1024);
    float*  cv = (float*)smem;
    int*    ci = (int*)(smem + 16 * 1024);
    const int t = threadIdx.x, tc = t & 31, tr = t >> 5;
    const int tok0 = blockIdx.x * 64;
    const float4* Xg = (const float4*)X;
    const float4* Eg = (const float4*)E;
    float v0[4], v1[4]; int i0[4], i1[4];
#pragma unroll
    for (int i = 0; i < 4; ++i) { v0[i] = -1e30f; v1[i] = -1e30f; i0[i] = 0; i1[i] = 1; }
    for (int kt = 0; kt < K_CODES / 128; ++kt) {
        float acc[4][4];
#pragma unroll
        for (int i = 0; i < 4; ++i)
#pragma unroll
            for (int j = 0; j < 4; ++j) acc[i][j] = 0.f;
        for (int dc = 0; dc < 8; ++dc) {
            __syncthreads();
#pragma unroll
            for (int s = 0; s < 2; ++s) {
                int id = t + s * 512; int rr = id >> 4, m = id & 15;
                Xs[rr * 16 + ((m + (rr >> 2)) & 15)] = Xg[(size_t)(tok0 + rr) * 128 + dc * 16 + m];
            }
#pragma unroll
            for (int s = 0; s < 4; ++s) {
                int id = t + s * 512; int rr = id >> 4, m = id & 15;
                Es[rr * 16 + ((m + (rr >> 2)) & 15)] = Eg[(size_t)(kt * 128 + rr) * 128 + dc * 16 + m];
            }
            __syncthreads();
#pragma unroll
            for (int dd4 = 0; dd4 < 16; ++dd4) {
                float4 xv[4], ev[4];
#pragma unroll
                for (int i = 0; i < 4; ++i) xv[i] = Xs[(4 * tr + i) * 16 + ((dd4 + tr) & 15)];
#pragma unroll
                for (int j = 0; j < 4; ++j) ev[j] = Es[(4 * tc + j) * 16 + ((dd4 + tc) & 15)];
#pragma unroll
                for (int i = 0; i < 4; ++i)
#pragma unroll
                    for (int j = 0; j < 4; ++j)
                        acc[i][j] += xv[i].x * ev[j].x + xv[i].y * ev[j].y + xv[i].z * ev[j].z + xv[i].w * ev[j].w;
            }
        }
#pragma unroll
        for (int i = 0; i < 4; ++i)
#pragma unroll
            for (int j = 0; j < 4; ++j) {
                float v = acc[i][j]; int idx = kt * 128 + 4 * tc + j;
                if (v > v0[i])      { v1[i] = v0[i]; i1[i] = i0[i]; v0[i] = v; i0[i] = idx; }
                else if (v > v1[i]) { v1[i] = v; i1[i] = idx; }
            }
    }
    __syncthreads();
#pragma unroll
    for (int i = 0; i < 4; ++i) {
        int row = 4 * tr + i;
        cv[row * 64 + 2 * tc] = v0[i];     ci[row * 64 + 2 * tc] = i0[i];
        cv[row * 64 + 2 * tc + 1] = v1[i]; ci[row * 64 + 2 * tc + 1] = i1[i];
    }
    __syncthreads();
    if (t < 64) {
        const int row = t;
        float b0 = -1e30f;
        for (int s = 0; s < 64; ++s) b0 = fmaxf(b0, cv[row * 64 + s]);
        const float* xr = X + (size_t)(tok0 + row) * D_DIM;
        const float sumx2 = np_pairwise_sq(xr);
        float bd = 1e30f; int bi = 0x7fffffff;
        for (int s = 0; s < 64; ++s) {
            float v = cv[row * 64 + s];
            if (v < b0 - 1.0e-4f) continue;
            int idx = ci[row * 64 + s];
            const float* er = E + (size_t)idx * D_DIM;
            double acc = 0.0;
            for (int d0 = 0; d0 < D_DIM; ++d0) acc += (double)xr[d0] * (double)er[d0];
            float M = (float)acc;
            float se2 = np_pairwise_sq(er);
            float S = sumx2 + se2;
            float d = S - 2.0f * M;
            if (d < bd || (d == bd && idx < bi)) { bd = d; bi = idx; }
        }
        out_idx[tok0 + row] = (float)bi;
    }
}

__global__ __launch_bounds__(256) void vq_gather_fb(
    const float* __restrict__ X, const float* __restrict__ E,
    const float* __restrict__ idxf, float* __restrict__ outq, float* __restrict__ outl)
{
    const int t = threadIdx.x;
    const int h = t >> 7, tt = t & 127;
    const int n = blockIdx.x * 2 + h;
    const int idx = (int)idxf[n];
    const float4* xr = (const float4*)(X + (size_t)n * D_DIM);
    const float4* er = (const float4*)(E + (size_t)idx * D_DIM);
    float4* qr = (float4*)(outq + (size_t)n * D_DIM);
    float4 x = xr[tt], e = er[tt];
    float4 dl; dl.x = e.x - x.x; dl.y = e.y - x.y; dl.z = e.z - x.z; dl.w = e.w - x.w;
    float4 qv; qv.x = x.x + dl.x; qv.y = x.y + dl.y; qv.z = x.z + dl.z; qv.w = x.w + dl.w;
    qr[tt] = qv;
    float s = dl.x * dl.x + dl.y * dl.y + dl.z * dl.z + dl.w * dl.w;
#pragma unroll
    for (int off = 32; off > 0; off >>= 1) s += __shfl_down(s, off, 64);
    __shared__ float red[4];
    if ((t & 63) == 0) red[t >> 6] = s;
    __syncthreads();
    if (tt == 0) {
        float m = (red[h * 2] + red[h * 2 + 1]) * (1.0f / (float)D_DIM);
        outl[n] = m + 0.25f * m;
    }
}

extern "C" void kernel_launch(void* const* d_in, const int* in_sizes, int n_in,
                              void* d_out, int out_size, void* d_ws, size_t ws_size,
                              hipStream_t stream) {
    const float* X = (const float*)d_in[0];
    const float* E = (const float*)d_in[1];
    float* out  = (float*)d_out;
    float* outq = out;
    float* outl = out + (size_t)N_TOK * D_DIM;
    float* outi = outl + N_TOK;

    const size_t WS_NEED = 33652736;  // Xim 16M + Eim 8M + vbuf 4M + ibuf 4M + sx/se
    if (ws_size >= WS_NEED) {
        unsigned char* ws = (unsigned char*)d_ws;
        unsigned char* Xim = ws;                        // 16MB
        unsigned char* Eim = ws + 16777216;             // 8MB
        float* vbuf = (float*)(ws + 25165824);          // 4MB
        int*   ibuf = (int*)(ws + 29360128);            // 4MB
        float* sx   = (float*)(ws + 33554432);          // 64KB
        float* se   = (float*)(ws + 33619968);          // 32KB
        vq_prep<<<9216, 256, 0, stream>>>(X, E, Xim, Eim, sx, se);
        vq_gemm<<<256, 512, 0, stream>>>(Xim, Eim, vbuf, ibuf);
        vq_refine<<<4096, 256, 0, stream>>>(X, E, vbuf, ibuf, sx, se, outi, outq, outl);
    } else {
        vq_argmin_fb<<<N_TOK / 64, 512, 0, stream>>>(X, E, outi);
        vq_gather_fb<<<8192, 256, 0, stream>>>(X, E, outi, outq, outl);
    }
}